// Round 5
// baseline (1671.105 us; speedup 1.0000x reference)
//
#include <hip/hip_runtime.h>
#include <stdint.h>

typedef unsigned short u16;
typedef __attribute__((ext_vector_type(8))) short bf16x8;
typedef __attribute__((ext_vector_type(4))) float f32x4;

#define NPTS 65536
#define NK27 27
#define KNN 16

__device__ __forceinline__ u16 f2b(float f) {
  union { float f; uint32_t u; } v; v.f = f;
  uint32_t r = (v.u + 0x7fffu + ((v.u >> 16) & 1u)) >> 16;
  return (u16)r;
}
__device__ __forceinline__ float b2f(u16 h) {
  union { uint32_t u; float f; } v; v.u = ((uint32_t)h) << 16; return v.f;
}

// dst[g][co][swz(ci)] (bf16) = src[g][ci][co] (f32); id is dst-linear.
// Swizzle: 16B-chunk c stored at c ^ (co & SWZB) so LDS reads are conflict-free.
__global__ __launch_bounds__(256) void wtrans(const float* __restrict__ src, u16* __restrict__ dst,
                                              int G, int CI, int CO) {
  int id = blockIdx.x * 256 + threadIdx.x;
  int tot = G * CI * CO;
  if (id >= tot) return;
  int cpr = CI / 8;
  int swzb = (cpr < 8 ? cpr : 8) - 1;
  int g = id / (CI * CO);
  int r = id - g * (CI * CO);
  int co = r / CI;
  int cis = r - co * CI;                    // swizzled ci position
  int c = cis / 8, e = cis - c * 8;
  int ci = (c ^ (co & swzb)) * 8 + e;       // source ci
  dst[id] = f2b(src[(size_t)g * CI * CO + (size_t)ci * CO + co]);
}

// W_in: [27][1][128] f32 -> dst[co][k32] bf16 (k padded 27->32, swizzled, CPR=4)
__global__ __launch_bounds__(256) void wtrans_in(const float* __restrict__ W, u16* __restrict__ dst) {
  int id = blockIdx.x * 256 + threadIdx.x;
  if (id >= 128 * 32) return;
  int co = id >> 5, cis = id & 31;
  int c = cis >> 3, e = cis & 7;
  int ci = ((c ^ (co & 3)) << 3) | e;
  dst[id] = (ci < NK27) ? f2b(W[ci * 128 + co]) : (u16)0;
}

// G[n][32] bf16 = gathered feats (k<27, idx<NPTS), else 0
__global__ __launch_bounds__(256) void g27(const float* __restrict__ feats, const int* __restrict__ nbr,
                                           u16* __restrict__ G) {
  int id = blockIdx.x * 256 + threadIdx.x;
  int n = id >> 5, j = id & 31;
  u16 v = 0;
  if (j < NK27) {
    int m = nbr[n * NK27 + j];
    if (m < NPTS) v = f2b(feats[m]);
  }
  G[id] = v;
}

// idx transpose: out[k][n] = nbr[n][k]
__global__ __launch_bounds__(256) void itrans(const int* __restrict__ nbr, int* __restrict__ out) {
  int id = blockIdx.x * 256 + threadIdx.x;
  int k = id >> 16;          // / NPTS
  int n = id & (NPTS - 1);
  out[id] = nbr[n * NK27 + k];
}

__global__ void zero_pads(u16* a, u16* b, u16* c, u16* d, u16* e) {
  int t = threadIdx.x;
  if (t < 128) { a[t] = 0; b[t] = 0; c[t] = 0; }
  if (t < 32) { d[t] = 0; e[t] = 0; }
}

#define GLDS16(g, l)                                                                        \
  __builtin_amdgcn_global_load_lds((const __attribute__((address_space(1))) void*)(g),      \
                                   (__attribute__((address_space(3))) void*)(l), 16, 0, 0)

// Gathered GEMM, BM=256, 8 waves, wave tile 64x64 (COUT>=128) or 32xCOUT.
// A: global->VGPR direct, 1-deep prefetch into opposite parity buffer.
// B: global->LDS once per tap (double-buffered, pre-swizzled Wt, swizzled ds_read).
// EMODE: 0=none 1=relu(v) 2=relu(v+res) 3=relu(v)+res
template<int CIN, int COUT, int NK, int EMODE, bool OUTF32>
__global__ __launch_bounds__(512, 2)
void sconv(const u16* __restrict__ x, const int* __restrict__ idxt,
           const u16* __restrict__ Wt, const float* __restrict__ bias,
           const u16* __restrict__ res, int res_stride,
           void* __restrict__ yout, int out_stride) {
  constexpr int BM = 256;
  constexpr int KK = CIN / 32;
  constexpr int CPR = CIN / 8;
  constexpr int SWZB = (CPR < 8 ? CPR : 8) - 1;
  constexpr int WAVES_N = (COUT >= 128) ? 2 : 1;
  constexpr int WN = COUT / WAVES_N;
  constexpr int N_REP = WN / 16;
  constexpr int WAVES_M = 8 / WAVES_N;
  constexpr int WM = BM / WAVES_M;           // 64 or 32
  constexpr int M_REP = WM / 16;
  constexpr int BSZ = COUT * CIN;
  constexpr int BCH = BSZ / 8;
  constexpr int BISS = (BCH + 511) / 512;

  __shared__ __attribute__((aligned(16))) u16 Bs[2][BSZ];

  const int tid = threadIdx.x;
  const int lane = tid & 63;
  const int wave = tid >> 6;
  const int n0 = blockIdx.x * BM;
  const int lr = lane & 15;
  const int lh = lane >> 4;
  const int wn = wave % WAVES_N;
  const int wm = wave / WAVES_N;
  const int row0 = wm * WM;
  const int col0 = wn * WN;

  f32x4 acc[M_REP][N_REP];
#pragma unroll
  for (int i = 0; i < M_REP; ++i)
#pragma unroll
    for (int j = 0; j < N_REP; ++j) acc[i][j] = (f32x4){0.f, 0.f, 0.f, 0.f};

  bf16x8 A0[M_REP][KK], A1[M_REP][KK];
  int mn[M_REP];

  auto stageB = [&](int k) {
    const u16* src = Wt + (size_t)k * BSZ;
    u16* dst = &Bs[k & 1][0];
#pragma unroll
    for (int i = 0; i < BISS; ++i) {
      int cb = i * 512 + wave * 64;          // wave-uniform chunk base
      if (BCH % 512 == 0 || cb < BCH)
        GLDS16(src + (size_t)(cb + lane) * 8, dst + (size_t)cb * 8);
    }
  };
  auto loadIdx = [&](int k, int (&m)[M_REP]) {
#pragma unroll
    for (int mr = 0; mr < M_REP; ++mr)
      m[mr] = idxt[(size_t)k * NPTS + n0 + row0 + mr * 16 + lr];
  };
  auto issueA = [&](const int (&m)[M_REP], bf16x8 (&dst)[M_REP][KK]) {
#pragma unroll
    for (int mr = 0; mr < M_REP; ++mr)
#pragma unroll
      for (int kk = 0; kk < KK; ++kk)
        dst[mr][kk] = *(const bf16x8*)(x + (size_t)m[mr] * CIN + kk * 32 + lh * 8);
  };
  auto compute = [&](int buf, const bf16x8 (&AR)[M_REP][KK]) {
#pragma unroll
    for (int kk = 0; kk < KK; ++kk) {
      bf16x8 b[N_REP];
      int pc = (kk * 4 + lh) ^ (lr & SWZB);  // swizzled chunk
#pragma unroll
      for (int nr = 0; nr < N_REP; ++nr)
        b[nr] = *(const bf16x8*)(&Bs[buf][(size_t)(col0 + nr * 16 + lr) * CIN + pc * 8]);
#pragma unroll
      for (int mr = 0; mr < M_REP; ++mr)
#pragma unroll
        for (int nr = 0; nr < N_REP; ++nr)
          acc[mr][nr] = __builtin_amdgcn_mfma_f32_16x16x32_bf16(AR[mr][kk], b[nr], acc[mr][nr], 0, 0, 0);
    }
  };

  // prologue: A(0)->A0, B(0)->Bs[0]; mn <- idx(1)
  {
    int m0[M_REP];
    if (NK == 1) {
#pragma unroll
      for (int mr = 0; mr < M_REP; ++mr) m0[mr] = n0 + row0 + mr * 16 + lr;
    } else {
      loadIdx(0, m0);
    }
    stageB(0);
    issueA(m0, A0);
    if (NK > 1) loadIdx(1, mn);
  }
  __syncthreads();

#define TAP(kv, AR, AW)                                                       \
  {                                                                           \
    const int k_ = (kv);                                                      \
    if (k_ + 1 < NK) {                                                        \
      issueA(mn, AW);                                                         \
      stageB(k_ + 1);                                                         \
      if (k_ + 2 < NK) loadIdx(k_ + 2, mn);                                   \
    }                                                                         \
    __builtin_amdgcn_sched_barrier(0);                                        \
    compute((k_) & 1, AR);                                                    \
    if (k_ + 1 < NK) __syncthreads();                                         \
  }

  if constexpr (NK == 1) {
    compute(0, A0);
  } else {
    int k = 0;
    for (; k + 2 < NK; k += 2) {
      TAP(k, A0, A1);
      TAP(k + 1, A1, A0);
    }
    TAP(k, A0, A1);  // NK odd: final tap
  }
#undef TAP

  // epilogue: C/D layout col=lane&15, row=(lane>>4)*4+j
#pragma unroll
  for (int mr = 0; mr < M_REP; ++mr) {
#pragma unroll
    for (int nr = 0; nr < N_REP; ++nr) {
      int col = col0 + nr * 16 + lr;
      float bv = bias ? bias[col] : 0.0f;
#pragma unroll
      for (int j = 0; j < 4; ++j) {
        int n = n0 + row0 + mr * 16 + lh * 4 + j;
        float v = acc[mr][nr][j] + bv;
        if (EMODE == 1) v = fmaxf(v, 0.0f);
        else if (EMODE == 2) v = fmaxf(v + b2f(res[(size_t)n * res_stride + col]), 0.0f);
        else if (EMODE == 3) v = fmaxf(v, 0.0f) + b2f(res[(size_t)n * res_stride + col]);
        if (OUTF32) ((float*)yout)[(size_t)n * out_stride + col] = v;
        else ((u16*)yout)[(size_t)n * out_stride + col] = f2b(v);
      }
    }
  }
}

// one wave per point: logits = (q . k_j)/sqrt(128); softmax; agg = sum a_j v_j
__global__ __launch_bounds__(256)
void attn_k(const u16* __restrict__ qb, const u16* __restrict__ kb,
            const u16* __restrict__ vb, const int* __restrict__ knn,
            u16* __restrict__ agg) {
  int n = (blockIdx.x * 256 + threadIdx.x) >> 6;
  int lane = threadIdx.x & 63;
  int c0 = lane * 2;
  uint32_t qp = *(const uint32_t*)(qb + (size_t)n * 128 + c0);
  float q0 = b2f((u16)(qp & 0xffff)), q1 = b2f((u16)(qp >> 16));
  float lg[KNN];
  int ms[KNN];
#pragma unroll
  for (int j = 0; j < KNN; ++j) {
    int m = knn[n * KNN + j];
    ms[j] = m;
    uint32_t kp = *(const uint32_t*)(kb + (size_t)m * 128 + c0);
    float p = q0 * b2f((u16)(kp & 0xffff)) + q1 * b2f((u16)(kp >> 16));
#pragma unroll
    for (int d = 1; d < 64; d <<= 1) p += __shfl_xor(p, d);
    lg[j] = p * 0.08838834764831845f;  // 128^-0.5
  }
  float mx = lg[0];
#pragma unroll
  for (int j = 1; j < KNN; ++j) mx = fmaxf(mx, lg[j]);
  float s = 0.f, w[KNN];
#pragma unroll
  for (int j = 0; j < KNN; ++j) { w[j] = __expf(lg[j] - mx); s += w[j]; }
  float inv = 1.0f / s;
  float a0 = 0.f, a1 = 0.f;
#pragma unroll
  for (int j = 0; j < KNN; ++j) {
    uint32_t vp = *(const uint32_t*)(vb + (size_t)ms[j] * 128 + c0);
    a0 += w[j] * b2f((u16)(vp & 0xffff));
    a1 += w[j] * b2f((u16)(vp >> 16));
  }
  a0 *= inv; a1 *= inv;
  uint32_t op = (uint32_t)f2b(a0) | ((uint32_t)f2b(a1) << 16);
  *(uint32_t*)(agg + (size_t)n * 128 + c0) = op;
}

extern "C" void kernel_launch(void* const* d_in, const int* in_sizes, int n_in,
                              void* d_out, int out_size, void* d_ws, size_t ws_size,
                              hipStream_t stream) {
  (void)in_sizes; (void)n_in; (void)out_size; (void)ws_size;
  const float* feats = (const float*)d_in[0];
  const int*   nbr   = (const int*)d_in[1];
  const int*   knn   = (const int*)d_in[2];
  const float* W_in  = (const float*)d_in[3];
  const float* b_in  = (const float*)d_in[4];
  const float* W_c0  = (const float*)d_in[5];
  const float* b_c0  = (const float*)d_in[6];
  const float* W_c1  = (const float*)d_in[7];
  const float* b_c1  = (const float*)d_in[8];
  const float* Wq    = (const float*)d_in[9];
  const float* Wk    = (const float*)d_in[10];
  const float* Wv    = (const float*)d_in[11];
  const float* Wo    = (const float*)d_in[12];
  const float* bo    = (const float*)d_in[13];
  const float* Wa0   = (const float*)d_in[14];
  const float* ba0   = (const float*)d_in[15];
  const float* Wa1   = (const float*)d_in[16];
  const float* ba1   = (const float*)d_in[17];
  const float* Wa2   = (const float*)d_in[18];
  const float* ba2   = (const float*)d_in[19];
  const float* Wb0   = (const float*)d_in[20];
  const float* bb0   = (const float*)d_in[21];
  const float* Wb1   = (const float*)d_in[22];
  const float* bb1   = (const float*)d_in[23];
  const float* W_out = (const float*)d_in[24];
  const float* b_out = (const float*)d_in[25];

  char* ws = (char*)d_ws;
  size_t off = 0;
  auto alloc = [&](size_t bytes) { size_t r = off; off += (bytes + 255) & ~(size_t)255; return r; };

  u16* wt_c0  = (u16*)(ws + alloc((size_t)81 * 16384 * 2));
  u16* wt_c1  = (u16*)(ws + alloc((size_t)81 * 16384 * 2));
  u16* wt_q   = (u16*)(ws + alloc((size_t)3 * 16384 * 2));
  u16* wt_k   = (u16*)(ws + alloc((size_t)3 * 16384 * 2));
  u16* wt_v   = (u16*)(ws + alloc((size_t)3 * 16384 * 2));
  u16* wt_o   = (u16*)(ws + alloc((size_t)3 * 16384 * 2));
  u16* wt_a0  = (u16*)(ws + alloc((size_t)3 * 128 * 32 * 2));
  u16* wt_a1  = (u16*)(ws + alloc((size_t)81 * 32 * 32 * 2));
  u16* wt_a2  = (u16*)(ws + alloc((size_t)3 * 32 * 64 * 2));
  u16* wt_b0  = (u16*)(ws + alloc((size_t)81 * 128 * 32 * 2));
  u16* wt_b1  = (u16*)(ws + alloc((size_t)81 * 32 * 64 * 2));
  u16* wt_out = (u16*)(ws + alloc((size_t)27 * 16384 * 2));
  u16* wt_in  = (u16*)(ws + alloc((size_t)128 * 32 * 2));
  int* idx_t  = (int*)(ws + alloc((size_t)NK27 * NPTS * 4));
  u16* G27    = (u16*)(ws + alloc((size_t)NPTS * 32 * 2));

  u16* B0 = (u16*)(ws + alloc((size_t)(NPTS + 1) * 128 * 2));  // "out" (gathered) — also AGG
  u16* B1 = (u16*)(ws + alloc((size_t)NPTS * 128 * 2));        // h (conv0 out)
  u16* KB = (u16*)(ws + alloc((size_t)(NPTS + 1) * 128 * 2));  // k-proj — also B2 (h2, gathered)
  u16* VB = (u16*)(ws + alloc((size_t)(NPTS + 1) * 128 * 2));  // v-proj — also B3 (x, gathered)
  u16* QB = (u16*)(ws + alloc((size_t)NPTS * 128 * 2));        // q-proj
  u16* H1 = (u16*)(ws + alloc((size_t)(NPTS + 1) * 32 * 2));   // a0 out (gathered)
  u16* HA = (u16*)(ws + alloc((size_t)NPTS * 32 * 2));         // a1 out
  u16* G  = (u16*)(ws + alloc((size_t)(NPTS + 1) * 32 * 2));   // b0 out (gathered)
  u16* AGG = B0;
  u16* B2 = KB;
  u16* B3 = VB;

  auto TG = [](int tot) { return (tot + 255) / 256; };
  // weight prep (bf16 + transpose + LDS swizzle)
  wtrans<<<TG(81 * 16384), 256, 0, stream>>>(W_c0, wt_c0, 81, 128, 128);
  wtrans<<<TG(81 * 16384), 256, 0, stream>>>(W_c1, wt_c1, 81, 128, 128);
  wtrans<<<TG(3 * 16384), 256, 0, stream>>>(Wq, wt_q, 3, 128, 128);
  wtrans<<<TG(3 * 16384), 256, 0, stream>>>(Wk, wt_k, 3, 128, 128);
  wtrans<<<TG(3 * 16384), 256, 0, stream>>>(Wv, wt_v, 3, 128, 128);
  wtrans<<<TG(3 * 16384), 256, 0, stream>>>(Wo, wt_o, 3, 128, 128);
  wtrans<<<TG(3 * 128 * 32), 256, 0, stream>>>(Wa0, wt_a0, 3, 128, 32);
  wtrans<<<TG(81 * 32 * 32), 256, 0, stream>>>(Wa1, wt_a1, 81, 32, 32);
  wtrans<<<TG(3 * 32 * 64), 256, 0, stream>>>(Wa2, wt_a2, 3, 32, 64);
  wtrans<<<TG(81 * 128 * 32), 256, 0, stream>>>(Wb0, wt_b0, 81, 128, 32);
  wtrans<<<TG(81 * 32 * 64), 256, 0, stream>>>(Wb1, wt_b1, 81, 32, 64);
  wtrans<<<TG(27 * 16384), 256, 0, stream>>>(W_out, wt_out, 27, 128, 128);
  wtrans_in<<<TG(128 * 32), 256, 0, stream>>>(W_in, wt_in);
  itrans<<<NK27 * NPTS / 256, 256, 0, stream>>>(nbr, idx_t);

  zero_pads<<<1, 256, 0, stream>>>(B0 + (size_t)NPTS * 128, KB + (size_t)NPTS * 128,
                                   VB + (size_t)NPTS * 128, H1 + (size_t)NPTS * 32,
                                   G + (size_t)NPTS * 32);

  // input conv: gather K=27 scalars -> G27[n][32], then MFMA GEMM
  g27<<<NPTS * 32 / 256, 256, 0, stream>>>(feats, nbr, G27);
  sconv<32, 128, 1, 0, false><<<NPTS / 256, 512, 0, stream>>>(G27, nullptr, wt_in, b_in, nullptr, 0, B0, 128);

  const int GB = NPTS / 256;  // 256 blocks, 1/CU
  for (int s = 0; s < 3; ++s) {
    const u16* wc0 = wt_c0 + (size_t)s * 27 * 16384;
    const u16* wc1 = wt_c1 + (size_t)s * 27 * 16384;
    const u16* wqs = wt_q + (size_t)s * 16384;
    const u16* wks = wt_k + (size_t)s * 16384;
    const u16* wvs = wt_v + (size_t)s * 16384;
    const u16* wos = wt_o + (size_t)s * 16384;
    const u16* wa0 = wt_a0 + (size_t)s * 4096;
    const u16* wa1 = wt_a1 + (size_t)s * 27648;
    const u16* wa2 = wt_a2 + (size_t)s * 2048;
    const u16* wb0 = wt_b0 + (size_t)s * 110592;
    const u16* wb1 = wt_b1 + (size_t)s * 55296;

    // h = sparse_conv(out, W_conv0)
    sconv<128, 128, 27, 0, false><<<GB, 512, 0, stream>>>(B0, idx_t, wc0, b_c0 + s * 128, nullptr, 0, B1, 128);
    // q,k,v
    sconv<128, 128, 1, 0, false><<<GB, 512, 0, stream>>>(B1, nullptr, wqs, nullptr, nullptr, 0, QB, 128);
    sconv<128, 128, 1, 0, false><<<GB, 512, 0, stream>>>(B1, nullptr, wks, nullptr, nullptr, 0, KB, 128);
    sconv<128, 128, 1, 0, false><<<GB, 512, 0, stream>>>(B1, nullptr, wvs, nullptr, nullptr, 0, VB, 128);
    attn_k<<<NPTS / 4, 256, 0, stream>>>(QB, KB, VB, knn, AGG);
    // h2 = relu(h + agg@Wo + bo)
    sconv<128, 128, 1, 2, false><<<GB, 512, 0, stream>>>(AGG, nullptr, wos, bo + s * 128, B1, 128, B2, 128);
    // x = sparse_conv(h2, W_conv1)
    sconv<128, 128, 27, 0, false><<<GB, 512, 0, stream>>>(B2, idx_t, wc1, b_c1 + s * 128, nullptr, 0, B3, 128);
    // irn
    sconv<128, 32, 1, 1, false><<<GB, 512, 0, stream>>>(B3, nullptr, wa0, ba0 + s * 32, nullptr, 0, H1, 32);
    sconv<32, 32, 27, 1, false><<<GB, 512, 0, stream>>>(H1, idx_t, wa1, ba1 + s * 32, nullptr, 0, HA, 32);
    sconv<32, 64, 1, 3, false><<<GB, 512, 0, stream>>>(HA, idx_t, wa2, ba2 + s * 64, B3, 128, B0, 128);
    sconv<128, 32, 27, 1, false><<<GB, 512, 0, stream>>>(B3, idx_t, wb0, bb0 + s * 32, nullptr, 0, G, 32);
    sconv<32, 64, 27, 3, false><<<GB, 512, 0, stream>>>(G, idx_t, wb1, bb1 + s * 64, B3 + 64, 128, (void*)(B0 + 64), 128);
  }
  // final conv -> fp32 d_out
  sconv<128, 128, 27, 0, true><<<GB, 512, 0, stream>>>(B0, idx_t, wt_out, b_out, nullptr, 0, d_out, 128);
}

// Round 6
// 1223.295 us; speedup vs baseline: 1.3661x; 1.3661x over previous
//
#include <hip/hip_runtime.h>
#include <stdint.h>

typedef unsigned short u16;
typedef __attribute__((ext_vector_type(8))) short bf16x8;
typedef __attribute__((ext_vector_type(4))) float f32x4;

#define NPTS 65536
#define NK27 27
#define KNN 16

__device__ __forceinline__ u16 f2b(float f) {
  union { float f; uint32_t u; } v; v.f = f;
  uint32_t r = (v.u + 0x7fffu + ((v.u >> 16) & 1u)) >> 16;
  return (u16)r;
}
__device__ __forceinline__ float b2f(u16 h) {
  union { uint32_t u; float f; } v; v.u = ((uint32_t)h) << 16; return v.f;
}

// wait until <=N VMEM ops outstanding (ignore lgkm/exp). gfx9 encoding.
template<int N>
__device__ __forceinline__ void waitcnt_vm() {
  __builtin_amdgcn_s_waitcnt((N & 0xF) | ((N >> 4) << 14) | (0x7 << 4) | (0xF << 8));
}

// dst[g][co][swz(ci)] (bf16) = src[g][ci][co] (f32); id is dst-linear.
__global__ __launch_bounds__(256) void wtrans(const float* __restrict__ src, u16* __restrict__ dst,
                                              int G, int CI, int CO) {
  int id = blockIdx.x * 256 + threadIdx.x;
  int tot = G * CI * CO;
  if (id >= tot) return;
  int cpr = CI / 8;
  int swzb = (cpr < 8 ? cpr : 8) - 1;
  int g = id / (CI * CO);
  int r = id - g * (CI * CO);
  int co = r / CI;
  int cis = r - co * CI;
  int c = cis / 8, e = cis - c * 8;
  int ci = (c ^ (co & swzb)) * 8 + e;
  dst[id] = f2b(src[(size_t)g * CI * CO + (size_t)ci * CO + co]);
}

// W_in: [27][1][128] f32 -> dst[co][k32] bf16 (k padded 27->32, swizzled, CPR=4)
__global__ __launch_bounds__(256) void wtrans_in(const float* __restrict__ W, u16* __restrict__ dst) {
  int id = blockIdx.x * 256 + threadIdx.x;
  if (id >= 128 * 32) return;
  int co = id >> 5, cis = id & 31;
  int c = cis >> 3, e = cis & 7;
  int ci = ((c ^ (co & 3)) << 3) | e;
  dst[id] = (ci < NK27) ? f2b(W[ci * 128 + co]) : (u16)0;
}

// G[n][32] bf16 = gathered feats (k<27, idx<NPTS), else 0
__global__ __launch_bounds__(256) void g27(const float* __restrict__ feats, const int* __restrict__ nbr,
                                           u16* __restrict__ G) {
  int id = blockIdx.x * 256 + threadIdx.x;
  int n = id >> 5, j = id & 31;
  u16 v = 0;
  if (j < NK27) {
    int m = nbr[n * NK27 + j];
    if (m < NPTS) v = f2b(feats[m]);
  }
  G[id] = v;
}

// idx transpose: out[k][n] = nbr[n][k]
__global__ __launch_bounds__(256) void itrans(const int* __restrict__ nbr, int* __restrict__ out) {
  int id = blockIdx.x * 256 + threadIdx.x;
  int k = id >> 16;
  int n = id & (NPTS - 1);
  out[id] = nbr[n * NK27 + k];
}

__global__ void zero_pads(u16* a, u16* b, u16* c, u16* d, u16* e) {
  int t = threadIdx.x;
  if (t < 128) { a[t] = 0; b[t] = 0; c[t] = 0; }
  if (t < 32) { d[t] = 0; e[t] = 0; }
}

#define GLDS16(g, l)                                                                        \
  __builtin_amdgcn_global_load_lds((const __attribute__((address_space(1))) void*)(g),      \
                                   (__attribute__((address_space(3))) void*)(l), 16, 0, 0)

// Gathered GEMM, BM=256, 8 waves, wave tile 32xCOUT (no A duplication).
// A: global->VGPR direct (gather IS the fragment load), double-buffered regs.
// B: global->LDS (double-buffered, pre-swizzled Wt, swizzled ds_read).
// Pipeline: raw s_barrier + counted vmcnt — prev tap's B-stage retires at the
// barrier while this tap's A-gathers + idx loads stay IN FLIGHT across it.
// EMODE: 0=none 1=relu(v) 2=relu(v+res) 3=relu(v)+res
template<int CIN, int COUT, int NK, int EMODE, bool OUTF32>
__global__ __launch_bounds__(512, 2)
void sconv(const u16* __restrict__ x, const int* __restrict__ idxt,
           const u16* __restrict__ Wt, const float* __restrict__ bias,
           const u16* __restrict__ res, int res_stride,
           void* __restrict__ yout, int out_stride) {
  static_assert(NK == 1 || ((NK - 1) % 2 == 0), "NK odd or 1");
  constexpr int BM = 256;
  constexpr int KK = CIN / 32;
  constexpr int CPR = CIN / 8;
  constexpr int SWZB = (CPR < 8 ? CPR : 8) - 1;
  constexpr int N_REP = COUT / 16;
  constexpr int M_REP = 2;                   // 32 rows per wave, 8 waves = 256
  constexpr int BSZ = COUT * CIN;
  constexpr int BCH = BSZ / 8;
  constexpr int BISS = (BCH + 511) / 512;
  constexpr int AC = M_REP * KK;             // A vmem ops per tap per wave
  constexpr int IC = M_REP;                  // idx vmem ops per tap per wave
  constexpr int VC_F = AC + IC;              // entry wait, generic tap
  constexpr int VC_L = AC;                   // entry wait, last tap

  __shared__ __attribute__((aligned(16))) u16 Bs[2][BSZ];

  const int tid = threadIdx.x;
  const int lane = tid & 63;
  const int wave = tid >> 6;
  const int n0 = blockIdx.x * BM;
  const int lr = lane & 15;
  const int lh = lane >> 4;
  const int row0 = wave * 32;

  f32x4 acc[M_REP][N_REP];
#pragma unroll
  for (int i = 0; i < M_REP; ++i)
#pragma unroll
    for (int j = 0; j < N_REP; ++j) acc[i][j] = (f32x4){0.f, 0.f, 0.f, 0.f};

  bf16x8 A0[M_REP][KK], A1[M_REP][KK];
  int mna[M_REP], mnb[M_REP];

  auto stageB = [&](int k, u16* dst) {
    const u16* src = Wt + (size_t)k * BSZ;
#pragma unroll
    for (int i = 0; i < BISS; ++i) {
      int cb = i * 512 + wave * 64;
      if (BCH % 512 == 0 || cb < BCH)
        GLDS16(src + (size_t)(cb + lane) * 8, dst + (size_t)cb * 8);
    }
  };
  auto loadIdx = [&](int k, int (&m)[M_REP]) {
#pragma unroll
    for (int mr = 0; mr < M_REP; ++mr)
      m[mr] = idxt[(size_t)k * NPTS + n0 + row0 + mr * 16 + lr];
  };
  auto issueA = [&](const int (&m)[M_REP], bf16x8 (&dst)[M_REP][KK]) {
#pragma unroll
    for (int mr = 0; mr < M_REP; ++mr)
#pragma unroll
      for (int kk = 0; kk < KK; ++kk)
        dst[mr][kk] = *(const bf16x8*)(x + (size_t)m[mr] * CIN + kk * 32 + lh * 8);
  };
  auto compute = [&](const u16* bsp, const bf16x8 (&AR)[M_REP][KK]) {
#pragma unroll
    for (int kk = 0; kk < KK; ++kk) {
      bf16x8 b[N_REP];
      int pc = (kk * 4 + lh) ^ (lr & SWZB);
#pragma unroll
      for (int nr = 0; nr < N_REP; ++nr)
        b[nr] = *(const bf16x8*)(bsp + (size_t)(nr * 16 + lr) * CIN + pc * 8);
#pragma unroll
      for (int mr = 0; mr < M_REP; ++mr)
#pragma unroll
        for (int nr = 0; nr < N_REP; ++nr)
          acc[mr][nr] = __builtin_amdgcn_mfma_f32_16x16x32_bf16(AR[mr][kk], b[nr], acc[mr][nr], 0, 0, 0);
    }
  };

  if constexpr (NK == 1) {
    int m0[M_REP];
#pragma unroll
    for (int mr = 0; mr < M_REP; ++mr) m0[mr] = n0 + row0 + mr * 16 + lr;
    stageB(0, &Bs[0][0]);
    issueA(m0, A0);
    __syncthreads();
    compute(&Bs[0][0], A0);
  } else {
    // prologue: pinned issue order idx(0) -> stage(0) -> A(0) -> idx(1)
    int m0[M_REP];
    loadIdx(0, m0);
    __builtin_amdgcn_sched_barrier(0);
    stageB(0, &Bs[0][0]);
    __builtin_amdgcn_sched_barrier(0);
    issueA(m0, A0);
    __builtin_amdgcn_sched_barrier(0);
    loadIdx(1, mnb);
    __builtin_amdgcn_sched_barrier(0);

#define TAPX(kv, P, ACUR, ANXT, MUSE, MWRT)                                   \
    {                                                                         \
      const int k_ = (kv);                                                    \
      __builtin_amdgcn_sched_barrier(0);                                      \
      waitcnt_vm<VC_F>();                                                     \
      __builtin_amdgcn_s_barrier();                                           \
      __builtin_amdgcn_sched_barrier(0);                                      \
      stageB(k_ + 1, &Bs[(P) ^ 1][0]);                                        \
      __builtin_amdgcn_sched_barrier(0);                                      \
      issueA(MUSE, ANXT);                                                     \
      __builtin_amdgcn_sched_barrier(0);                                      \
      if (k_ + 2 < NK) loadIdx(k_ + 2, MWRT);                                 \
      __builtin_amdgcn_sched_barrier(0);                                      \
      compute(&Bs[P][0], ACUR);                                               \
    }

    for (int k = 0; k < NK - 1; k += 2) {
      TAPX(k, 0, A0, A1, mnb, mna);
      TAPX(k + 1, 1, A1, A0, mna, mnb);
    }
#undef TAPX
    // last tap (NK-1 even -> parity 0, A0)
    __builtin_amdgcn_sched_barrier(0);
    waitcnt_vm<VC_L>();
    __builtin_amdgcn_s_barrier();
    __builtin_amdgcn_sched_barrier(0);
    compute(&Bs[0][0], A0);
  }

  // epilogue: C/D layout col=lane&15, row=(lane>>4)*4+j
#pragma unroll
  for (int mr = 0; mr < M_REP; ++mr) {
#pragma unroll
    for (int nr = 0; nr < N_REP; ++nr) {
      int col = nr * 16 + lr;
      float bv = bias ? bias[col] : 0.0f;
#pragma unroll
      for (int j = 0; j < 4; ++j) {
        int n = n0 + row0 + mr * 16 + lh * 4 + j;
        float v = acc[mr][nr][j] + bv;
        if (EMODE == 1) v = fmaxf(v, 0.0f);
        else if (EMODE == 2) v = fmaxf(v + b2f(res[(size_t)n * res_stride + col]), 0.0f);
        else if (EMODE == 3) v = fmaxf(v, 0.0f) + b2f(res[(size_t)n * res_stride + col]);
        if (OUTF32) ((float*)yout)[(size_t)n * out_stride + col] = v;
        else ((u16*)yout)[(size_t)n * out_stride + col] = f2b(v);
      }
    }
  }
}

// one wave per point: logits = (q . k_j)/sqrt(128); softmax; agg = sum a_j v_j
__global__ __launch_bounds__(256)
void attn_k(const u16* __restrict__ qb, const u16* __restrict__ kb,
            const u16* __restrict__ vb, const int* __restrict__ knn,
            u16* __restrict__ agg) {
  int n = (blockIdx.x * 256 + threadIdx.x) >> 6;
  int lane = threadIdx.x & 63;
  int c0 = lane * 2;
  uint32_t qp = *(const uint32_t*)(qb + (size_t)n * 128 + c0);
  float q0 = b2f((u16)(qp & 0xffff)), q1 = b2f((u16)(qp >> 16));
  float lg[KNN];
  int ms[KNN];
#pragma unroll
  for (int j = 0; j < KNN; ++j) {
    int m = knn[n * KNN + j];
    ms[j] = m;
    uint32_t kp = *(const uint32_t*)(kb + (size_t)m * 128 + c0);
    float p = q0 * b2f((u16)(kp & 0xffff)) + q1 * b2f((u16)(kp >> 16));
#pragma unroll
    for (int d = 1; d < 64; d <<= 1) p += __shfl_xor(p, d);
    lg[j] = p * 0.08838834764831845f;  // 128^-0.5
  }
  float mx = lg[0];
#pragma unroll
  for (int j = 1; j < KNN; ++j) mx = fmaxf(mx, lg[j]);
  float s = 0.f, w[KNN];
#pragma unroll
  for (int j = 0; j < KNN; ++j) { w[j] = __expf(lg[j] - mx); s += w[j]; }
  float inv = 1.0f / s;
  float a0 = 0.f, a1 = 0.f;
#pragma unroll
  for (int j = 0; j < KNN; ++j) {
    uint32_t vp = *(const uint32_t*)(vb + (size_t)ms[j] * 128 + c0);
    a0 += w[j] * b2f((u16)(vp & 0xffff));
    a1 += w[j] * b2f((u16)(vp >> 16));
  }
  a0 *= inv; a1 *= inv;
  uint32_t op = (uint32_t)f2b(a0) | ((uint32_t)f2b(a1) << 16);
  *(uint32_t*)(agg + (size_t)n * 128 + c0) = op;
}

extern "C" void kernel_launch(void* const* d_in, const int* in_sizes, int n_in,
                              void* d_out, int out_size, void* d_ws, size_t ws_size,
                              hipStream_t stream) {
  (void)in_sizes; (void)n_in; (void)out_size; (void)ws_size;
  const float* feats = (const float*)d_in[0];
  const int*   nbr   = (const int*)d_in[1];
  const int*   knn   = (const int*)d_in[2];
  const float* W_in  = (const float*)d_in[3];
  const float* b_in  = (const float*)d_in[4];
  const float* W_c0  = (const float*)d_in[5];
  const float* b_c0  = (const float*)d_in[6];
  const float* W_c1  = (const float*)d_in[7];
  const float* b_c1  = (const float*)d_in[8];
  const float* Wq    = (const float*)d_in[9];
  const float* Wk    = (const float*)d_in[10];
  const float* Wv    = (const float*)d_in[11];
  const float* Wo    = (const float*)d_in[12];
  const float* bo    = (const float*)d_in[13];
  const float* Wa0   = (const float*)d_in[14];
  const float* ba0   = (const float*)d_in[15];
  const float* Wa1   = (const float*)d_in[16];
  const float* ba1   = (const float*)d_in[17];
  const float* Wa2   = (const float*)d_in[18];
  const float* ba2   = (const float*)d_in[19];
  const float* Wb0   = (const float*)d_in[20];
  const float* bb0   = (const float*)d_in[21];
  const float* Wb1   = (const float*)d_in[22];
  const float* bb1   = (const float*)d_in[23];
  const float* W_out = (const float*)d_in[24];
  const float* b_out = (const float*)d_in[25];

  char* ws = (char*)d_ws;
  size_t off = 0;
  auto alloc = [&](size_t bytes) { size_t r = off; off += (bytes + 255) & ~(size_t)255; return r; };

  u16* wt_c0  = (u16*)(ws + alloc((size_t)81 * 16384 * 2));
  u16* wt_c1  = (u16*)(ws + alloc((size_t)81 * 16384 * 2));
  u16* wt_q   = (u16*)(ws + alloc((size_t)3 * 16384 * 2));
  u16* wt_k   = (u16*)(ws + alloc((size_t)3 * 16384 * 2));
  u16* wt_v   = (u16*)(ws + alloc((size_t)3 * 16384 * 2));
  u16* wt_o   = (u16*)(ws + alloc((size_t)3 * 16384 * 2));
  u16* wt_a0  = (u16*)(ws + alloc((size_t)3 * 128 * 32 * 2));
  u16* wt_a1  = (u16*)(ws + alloc((size_t)81 * 32 * 32 * 2));
  u16* wt_a2  = (u16*)(ws + alloc((size_t)3 * 32 * 64 * 2));
  u16* wt_b0  = (u16*)(ws + alloc((size_t)81 * 128 * 32 * 2));
  u16* wt_b1  = (u16*)(ws + alloc((size_t)81 * 32 * 64 * 2));
  u16* wt_out = (u16*)(ws + alloc((size_t)27 * 16384 * 2));
  u16* wt_in  = (u16*)(ws + alloc((size_t)128 * 32 * 2));
  int* idx_t  = (int*)(ws + alloc((size_t)NK27 * NPTS * 4));
  u16* G27    = (u16*)(ws + alloc((size_t)NPTS * 32 * 2));

  u16* B0 = (u16*)(ws + alloc((size_t)(NPTS + 1) * 128 * 2));  // "out" (gathered) — also AGG
  u16* B1 = (u16*)(ws + alloc((size_t)NPTS * 128 * 2));        // h (conv0 out)
  u16* KB = (u16*)(ws + alloc((size_t)(NPTS + 1) * 128 * 2));  // k-proj — also B2 (h2, gathered)
  u16* VB = (u16*)(ws + alloc((size_t)(NPTS + 1) * 128 * 2));  // v-proj — also B3 (x, gathered)
  u16* QB = (u16*)(ws + alloc((size_t)NPTS * 128 * 2));        // q-proj
  u16* H1 = (u16*)(ws + alloc((size_t)(NPTS + 1) * 32 * 2));   // a0 out (gathered)
  u16* HA = (u16*)(ws + alloc((size_t)NPTS * 32 * 2));         // a1 out
  u16* G  = (u16*)(ws + alloc((size_t)(NPTS + 1) * 32 * 2));   // b0 out (gathered)
  u16* AGG = B0;
  u16* B2 = KB;
  u16* B3 = VB;

  auto TG = [](int tot) { return (tot + 255) / 256; };
  // weight prep (bf16 + transpose + LDS swizzle)
  wtrans<<<TG(81 * 16384), 256, 0, stream>>>(W_c0, wt_c0, 81, 128, 128);
  wtrans<<<TG(81 * 16384), 256, 0, stream>>>(W_c1, wt_c1, 81, 128, 128);
  wtrans<<<TG(3 * 16384), 256, 0, stream>>>(Wq, wt_q, 3, 128, 128);
  wtrans<<<TG(3 * 16384), 256, 0, stream>>>(Wk, wt_k, 3, 128, 128);
  wtrans<<<TG(3 * 16384), 256, 0, stream>>>(Wv, wt_v, 3, 128, 128);
  wtrans<<<TG(3 * 16384), 256, 0, stream>>>(Wo, wt_o, 3, 128, 128);
  wtrans<<<TG(3 * 128 * 32), 256, 0, stream>>>(Wa0, wt_a0, 3, 128, 32);
  wtrans<<<TG(81 * 32 * 32), 256, 0, stream>>>(Wa1, wt_a1, 81, 32, 32);
  wtrans<<<TG(3 * 32 * 64), 256, 0, stream>>>(Wa2, wt_a2, 3, 32, 64);
  wtrans<<<TG(81 * 128 * 32), 256, 0, stream>>>(Wb0, wt_b0, 81, 128, 32);
  wtrans<<<TG(81 * 32 * 64), 256, 0, stream>>>(Wb1, wt_b1, 81, 32, 64);
  wtrans<<<TG(27 * 16384), 256, 0, stream>>>(W_out, wt_out, 27, 128, 128);
  wtrans_in<<<TG(128 * 32), 256, 0, stream>>>(W_in, wt_in);
  itrans<<<NK27 * NPTS / 256, 256, 0, stream>>>(nbr, idx_t);

  zero_pads<<<1, 256, 0, stream>>>(B0 + (size_t)NPTS * 128, KB + (size_t)NPTS * 128,
                                   VB + (size_t)NPTS * 128, H1 + (size_t)NPTS * 32,
                                   G + (size_t)NPTS * 32);

  // input conv: gather K=27 scalars -> G27[n][32], then MFMA GEMM
  g27<<<NPTS * 32 / 256, 256, 0, stream>>>(feats, nbr, G27);
  sconv<32, 128, 1, 0, false><<<NPTS / 256, 512, 0, stream>>>(G27, nullptr, wt_in, b_in, nullptr, 0, B0, 128);

  const int GB = NPTS / 256;  // 256 blocks, 1/CU
  for (int s = 0; s < 3; ++s) {
    const u16* wc0 = wt_c0 + (size_t)s * 27 * 16384;
    const u16* wc1 = wt_c1 + (size_t)s * 27 * 16384;
    const u16* wqs = wt_q + (size_t)s * 16384;
    const u16* wks = wt_k + (size_t)s * 16384;
    const u16* wvs = wt_v + (size_t)s * 16384;
    const u16* wos = wt_o + (size_t)s * 16384;
    const u16* wa0 = wt_a0 + (size_t)s * 4096;
    const u16* wa1 = wt_a1 + (size_t)s * 27648;
    const u16* wa2 = wt_a2 + (size_t)s * 2048;
    const u16* wb0 = wt_b0 + (size_t)s * 110592;
    const u16* wb1 = wt_b1 + (size_t)s * 55296;

    // h = sparse_conv(out, W_conv0)
    sconv<128, 128, 27, 0, false><<<GB, 512, 0, stream>>>(B0, idx_t, wc0, b_c0 + s * 128, nullptr, 0, B1, 128);
    // q,k,v
    sconv<128, 128, 1, 0, false><<<GB, 512, 0, stream>>>(B1, nullptr, wqs, nullptr, nullptr, 0, QB, 128);
    sconv<128, 128, 1, 0, false><<<GB, 512, 0, stream>>>(B1, nullptr, wks, nullptr, nullptr, 0, KB, 128);
    sconv<128, 128, 1, 0, false><<<GB, 512, 0, stream>>>(B1, nullptr, wvs, nullptr, nullptr, 0, VB, 128);
    attn_k<<<NPTS / 4, 256, 0, stream>>>(QB, KB, VB, knn, AGG);
    // h2 = relu(h + agg@Wo + bo)
    sconv<128, 128, 1, 2, false><<<GB, 512, 0, stream>>>(AGG, nullptr, wos, bo + s * 128, B1, 128, B2, 128);
    // x = sparse_conv(h2, W_conv1)
    sconv<128, 128, 27, 0, false><<<GB, 512, 0, stream>>>(B2, idx_t, wc1, b_c1 + s * 128, nullptr, 0, B3, 128);
    // irn
    sconv<128, 32, 1, 1, false><<<GB, 512, 0, stream>>>(B3, nullptr, wa0, ba0 + s * 32, nullptr, 0, H1, 32);
    sconv<32, 32, 27, 1, false><<<GB, 512, 0, stream>>>(H1, idx_t, wa1, ba1 + s * 32, nullptr, 0, HA, 32);
    sconv<32, 64, 1, 3, false><<<GB, 512, 0, stream>>>(HA, idx_t, wa2, ba2 + s * 64, B3, 128, B0, 128);
    sconv<128, 32, 27, 1, false><<<GB, 512, 0, stream>>>(B3, idx_t, wb0, bb0 + s * 32, nullptr, 0, G, 32);
    sconv<32, 64, 27, 3, false><<<GB, 512, 0, stream>>>(G, idx_t, wb1, bb1 + s * 64, B3 + 64, 128, (void*)(B0 + 64), 128);
  }
  // final conv -> fp32 d_out
  sconv<128, 128, 27, 0, true><<<GB, 512, 0, stream>>>(B0, idx_t, wt_out, b_out, nullptr, 0, d_out, 128);
}

// Round 7
// 1204.493 us; speedup vs baseline: 1.3874x; 1.0156x over previous
//
#include <hip/hip_runtime.h>
#include <stdint.h>

typedef unsigned short u16;
typedef __attribute__((ext_vector_type(8))) short bf16x8;
typedef __attribute__((ext_vector_type(4))) float f32x4;

#define NPTS 65536
#define NK27 27
#define KNN 16

__device__ __forceinline__ u16 f2b(float f) {
  union { float f; uint32_t u; } v; v.f = f;
  uint32_t r = (v.u + 0x7fffu + ((v.u >> 16) & 1u)) >> 16;
  return (u16)r;
}
__device__ __forceinline__ float b2f(u16 h) {
  union { uint32_t u; float f; } v; v.u = ((uint32_t)h) << 16; return v.f;
}

// wait until <=N VMEM ops outstanding (ignore lgkm/exp). gfx9 encoding.
template<int N>
__device__ __forceinline__ void waitcnt_vm() {
  __builtin_amdgcn_s_waitcnt((N & 0xF) | ((N >> 4) << 14) | (0x7 << 4) | (0xF << 8));
}

// dst[g][co][swz(ci)] (bf16) = src[g][ci][co] (f32); id is dst-linear.
__global__ __launch_bounds__(256) void wtrans(const float* __restrict__ src, u16* __restrict__ dst,
                                              int G, int CI, int CO) {
  int id = blockIdx.x * 256 + threadIdx.x;
  int tot = G * CI * CO;
  if (id >= tot) return;
  int cpr = CI / 8;
  int swzb = (cpr < 8 ? cpr : 8) - 1;
  int g = id / (CI * CO);
  int r = id - g * (CI * CO);
  int co = r / CI;
  int cis = r - co * CI;
  int c = cis / 8, e = cis - c * 8;
  int ci = (c ^ (co & swzb)) * 8 + e;
  dst[id] = f2b(src[(size_t)g * CI * CO + (size_t)ci * CO + co]);
}

// W_in: [27][1][128] f32 -> dst[co][k32] bf16 (k padded 27->32, swizzled, CPR=4)
__global__ __launch_bounds__(256) void wtrans_in(const float* __restrict__ W, u16* __restrict__ dst) {
  int id = blockIdx.x * 256 + threadIdx.x;
  if (id >= 128 * 32) return;
  int co = id >> 5, cis = id & 31;
  int c = cis >> 3, e = cis & 7;
  int ci = ((c ^ (co & 3)) << 3) | e;
  dst[id] = (ci < NK27) ? f2b(W[ci * 128 + co]) : (u16)0;
}

// G[n][32] bf16 = gathered feats (k<27, idx<NPTS), else 0
__global__ __launch_bounds__(256) void g27(const float* __restrict__ feats, const int* __restrict__ nbr,
                                           u16* __restrict__ G) {
  int id = blockIdx.x * 256 + threadIdx.x;
  int n = id >> 5, j = id & 31;
  u16 v = 0;
  if (j < NK27) {
    int m = nbr[n * NK27 + j];
    if (m < NPTS) v = f2b(feats[m]);
  }
  G[id] = v;
}

// idx transpose: out[k][n] = nbr[n][k]
__global__ __launch_bounds__(256) void itrans(const int* __restrict__ nbr, int* __restrict__ out) {
  int id = blockIdx.x * 256 + threadIdx.x;
  int k = id >> 16;
  int n = id & (NPTS - 1);
  out[id] = nbr[n * NK27 + k];
}

__global__ void zero_pads(u16* a, u16* b, u16* c, u16* d, u16* e) {
  int t = threadIdx.x;
  if (t < 128) { a[t] = 0; b[t] = 0; c[t] = 0; }
  if (t < 32) { d[t] = 0; e[t] = 0; }
}

#define GLDS16(g, l)                                                                        \
  __builtin_amdgcn_global_load_lds((const __attribute__((address_space(1))) void*)(g),      \
                                   (__attribute__((address_space(3))) void*)(l), 16, 0, 0)

// Gathered GEMM, BM=256, 8 waves, wave tile 32xCOUT (no A duplication).
// A: global->VGPR direct; B: global->LDS double-buffered; counted-vmcnt barriers.
// EMODE: 0=none 1=relu(v) 2=relu(v+res) 3=relu(v)+res
template<int CIN, int COUT, int NK, int EMODE, bool OUTF32>
__global__ __launch_bounds__(512, 2)
void sconv(const u16* __restrict__ x, const int* __restrict__ idxt,
           const u16* __restrict__ Wt, const float* __restrict__ bias,
           const u16* __restrict__ res, int res_stride,
           void* __restrict__ yout, int out_stride) {
  static_assert(NK == 1 || ((NK - 1) % 2 == 0), "NK odd or 1");
  constexpr int BM = 256;
  constexpr int KK = CIN / 32;
  constexpr int CPR = CIN / 8;
  constexpr int SWZB = (CPR < 8 ? CPR : 8) - 1;
  constexpr int N_REP = COUT / 16;
  constexpr int M_REP = 2;
  constexpr int BSZ = COUT * CIN;
  constexpr int BCH = BSZ / 8;
  constexpr int BISS = (BCH + 511) / 512;
  constexpr int AC = M_REP * KK;
  constexpr int IC = M_REP;
  constexpr int VC_F = AC + IC;
  constexpr int VC_L = AC;

  __shared__ __attribute__((aligned(16))) u16 Bs[2][BSZ];

  const int tid = threadIdx.x;
  const int lane = tid & 63;
  const int wave = tid >> 6;
  const int n0 = blockIdx.x * BM;
  const int lr = lane & 15;
  const int lh = lane >> 4;
  const int row0 = wave * 32;

  f32x4 acc[M_REP][N_REP];
#pragma unroll
  for (int i = 0; i < M_REP; ++i)
#pragma unroll
    for (int j = 0; j < N_REP; ++j) acc[i][j] = (f32x4){0.f, 0.f, 0.f, 0.f};

  bf16x8 A0[M_REP][KK], A1[M_REP][KK];
  int mna[M_REP], mnb[M_REP];

  auto stageB = [&](int k, u16* dst) {
    const u16* src = Wt + (size_t)k * BSZ;
#pragma unroll
    for (int i = 0; i < BISS; ++i) {
      int cb = i * 512 + wave * 64;
      if (BCH % 512 == 0 || cb < BCH)
        GLDS16(src + (size_t)(cb + lane) * 8, dst + (size_t)cb * 8);
    }
  };
  auto loadIdx = [&](int k, int (&m)[M_REP]) {
#pragma unroll
    for (int mr = 0; mr < M_REP; ++mr)
      m[mr] = idxt[(size_t)k * NPTS + n0 + row0 + mr * 16 + lr];
  };
  auto issueA = [&](const int (&m)[M_REP], bf16x8 (&dst)[M_REP][KK]) {
#pragma unroll
    for (int mr = 0; mr < M_REP; ++mr)
#pragma unroll
      for (int kk = 0; kk < KK; ++kk)
        dst[mr][kk] = *(const bf16x8*)(x + (size_t)m[mr] * CIN + kk * 32 + lh * 8);
  };
  auto compute = [&](const u16* bsp, const bf16x8 (&AR)[M_REP][KK]) {
#pragma unroll
    for (int kk = 0; kk < KK; ++kk) {
      bf16x8 b[N_REP];
      int pc = (kk * 4 + lh) ^ (lr & SWZB);
#pragma unroll
      for (int nr = 0; nr < N_REP; ++nr)
        b[nr] = *(const bf16x8*)(bsp + (size_t)(nr * 16 + lr) * CIN + pc * 8);
#pragma unroll
      for (int mr = 0; mr < M_REP; ++mr)
#pragma unroll
        for (int nr = 0; nr < N_REP; ++nr)
          acc[mr][nr] = __builtin_amdgcn_mfma_f32_16x16x32_bf16(AR[mr][kk], b[nr], acc[mr][nr], 0, 0, 0);
    }
  };

  if constexpr (NK == 1) {
    int m0[M_REP];
#pragma unroll
    for (int mr = 0; mr < M_REP; ++mr) m0[mr] = n0 + row0 + mr * 16 + lr;
    stageB(0, &Bs[0][0]);
    issueA(m0, A0);
    __syncthreads();
    compute(&Bs[0][0], A0);
  } else {
    int m0[M_REP];
    loadIdx(0, m0);
    __builtin_amdgcn_sched_barrier(0);
    stageB(0, &Bs[0][0]);
    __builtin_amdgcn_sched_barrier(0);
    issueA(m0, A0);
    __builtin_amdgcn_sched_barrier(0);
    loadIdx(1, mnb);
    __builtin_amdgcn_sched_barrier(0);

#define TAPX(kv, P, ACUR, ANXT, MUSE, MWRT)                                   \
    {                                                                         \
      const int k_ = (kv);                                                    \
      __builtin_amdgcn_sched_barrier(0);                                      \
      waitcnt_vm<VC_F>();                                                     \
      __builtin_amdgcn_s_barrier();                                           \
      __builtin_amdgcn_sched_barrier(0);                                      \
      stageB(k_ + 1, &Bs[(P) ^ 1][0]);                                        \
      __builtin_amdgcn_sched_barrier(0);                                      \
      issueA(MUSE, ANXT);                                                     \
      __builtin_amdgcn_sched_barrier(0);                                      \
      if (k_ + 2 < NK) loadIdx(k_ + 2, MWRT);                                 \
      __builtin_amdgcn_sched_barrier(0);                                      \
      compute(&Bs[P][0], ACUR);                                               \
    }

    for (int k = 0; k < NK - 1; k += 2) {
      TAPX(k, 0, A0, A1, mnb, mna);
      TAPX(k + 1, 1, A1, A0, mna, mnb);
    }
#undef TAPX
    __builtin_amdgcn_sched_barrier(0);
    waitcnt_vm<VC_L>();
    __builtin_amdgcn_s_barrier();
    __builtin_amdgcn_sched_barrier(0);
    compute(&Bs[0][0], A0);
  }

#pragma unroll
  for (int mr = 0; mr < M_REP; ++mr) {
#pragma unroll
    for (int nr = 0; nr < N_REP; ++nr) {
      int col = nr * 16 + lr;
      float bv = bias ? bias[col] : 0.0f;
#pragma unroll
      for (int j = 0; j < 4; ++j) {
        int n = n0 + row0 + mr * 16 + lh * 4 + j;
        float v = acc[mr][nr][j] + bv;
        if (EMODE == 1) v = fmaxf(v, 0.0f);
        else if (EMODE == 2) v = fmaxf(v + b2f(res[(size_t)n * res_stride + col]), 0.0f);
        else if (EMODE == 3) v = fmaxf(v, 0.0f) + b2f(res[(size_t)n * res_stride + col]);
        if (OUTF32) ((float*)yout)[(size_t)n * out_stride + col] = v;
        else ((u16*)yout)[(size_t)n * out_stride + col] = f2b(v);
      }
    }
  }
}

// Fused q/k/v projections: A rows loaded to regs ONCE, 3 weight slabs staged
// through one LDS buffer sequentially. x: [NPTS][128]; Wt: 3 slabs of [128][128].
__global__ __launch_bounds__(512, 2)
void qkv_k(const u16* __restrict__ x, const u16* __restrict__ Wt,
           u16* __restrict__ qo, u16* __restrict__ ko, u16* __restrict__ vo) {
  constexpr int CIN = 128, COUT = 128;
  constexpr int KK = 4, SWZB = 7, N_REP = 8, M_REP = 2;
  constexpr int BSZ = COUT * CIN;   // 16384 elems = 32KB
  constexpr int BISS = (BSZ / 8) / 512;  // 4

  __shared__ __attribute__((aligned(16))) u16 Bs[BSZ];

  const int tid = threadIdx.x;
  const int lane = tid & 63;
  const int wave = tid >> 6;
  const int n0 = blockIdx.x * 256;
  const int lr = lane & 15;
  const int lh = lane >> 4;
  const int row0 = wave * 32;

  bf16x8 A0[M_REP][KK];
#pragma unroll
  for (int mr = 0; mr < M_REP; ++mr)
#pragma unroll
    for (int kk = 0; kk < KK; ++kk)
      A0[mr][kk] = *(const bf16x8*)(x + (size_t)(n0 + row0 + mr * 16 + lr) * CIN + kk * 32 + lh * 8);

  u16* outs[3] = {qo, ko, vo};
  for (int w = 0; w < 3; ++w) {
    if (w) __syncthreads();  // all waves done reading Bs before restage
    const u16* src = Wt + (size_t)w * BSZ;
#pragma unroll
    for (int i = 0; i < BISS; ++i) {
      int cb = i * 512 + wave * 64;
      GLDS16(src + (size_t)(cb + lane) * 8, &Bs[(size_t)cb * 8]);
    }
    __syncthreads();  // drains stage (vmcnt0)

    f32x4 acc[M_REP][N_REP];
#pragma unroll
    for (int i = 0; i < M_REP; ++i)
#pragma unroll
      for (int j = 0; j < N_REP; ++j) acc[i][j] = (f32x4){0.f, 0.f, 0.f, 0.f};
#pragma unroll
    for (int kk = 0; kk < KK; ++kk) {
      bf16x8 b[N_REP];
      int pc = (kk * 4 + lh) ^ (lr & SWZB);
#pragma unroll
      for (int nr = 0; nr < N_REP; ++nr)
        b[nr] = *(const bf16x8*)(&Bs[(size_t)(nr * 16 + lr) * CIN + pc * 8]);
#pragma unroll
      for (int mr = 0; mr < M_REP; ++mr)
#pragma unroll
        for (int nr = 0; nr < N_REP; ++nr)
          acc[mr][nr] = __builtin_amdgcn_mfma_f32_16x16x32_bf16(A0[mr][kk], b[nr], acc[mr][nr], 0, 0, 0);
    }
    u16* yo = outs[w];
#pragma unroll
    for (int mr = 0; mr < M_REP; ++mr)
#pragma unroll
      for (int nr = 0; nr < N_REP; ++nr) {
        int col = nr * 16 + lr;
#pragma unroll
        for (int j = 0; j < 4; ++j) {
          int n = n0 + row0 + mr * 16 + lh * 4 + j;
          yo[(size_t)n * 128 + col] = f2b(acc[mr][nr][j]);
        }
      }
  }
}

// kNN attention: 16 lanes per point, 4 points per wave.
// lane s of a group holds channels 8s..8s+7; per j the group loads one 256B
// K/V row coalesced; dot reduced over 16 lanes (4 shfl_xor steps).
__global__ __launch_bounds__(256)
void attn_k(const u16* __restrict__ qb, const u16* __restrict__ kb,
            const u16* __restrict__ vb, const int* __restrict__ knn,
            u16* __restrict__ agg) {
  const int t = blockIdx.x * 256 + threadIdx.x;
  const int n = t >> 4;
  const int s = t & 15;
  const int lane = threadIdx.x & 63;
  const int gbase = lane & 48;

  int myidx = knn[n * KNN + s];  // lane s holds neighbor index j=s for point n

  bf16x8 q8 = *(const bf16x8*)(qb + (size_t)n * 128 + s * 8);
  float qf[8];
#pragma unroll
  for (int c = 0; c < 4; ++c) {
    uint32_t u = ((const uint32_t*)&q8)[c];
    qf[2 * c] = b2f((u16)(u & 0xffff));
    qf[2 * c + 1] = b2f((u16)(u >> 16));
  }

  float lg[KNN];
  int ms[KNN];
#pragma unroll
  for (int j = 0; j < KNN; ++j) {
    int mj = __shfl(myidx, gbase | j);
    ms[j] = mj;
    bf16x8 k8 = *(const bf16x8*)(kb + (size_t)mj * 128 + s * 8);
    float d = 0.f;
#pragma unroll
    for (int c = 0; c < 4; ++c) {
      uint32_t u = ((const uint32_t*)&k8)[c];
      d += qf[2 * c] * b2f((u16)(u & 0xffff));
      d += qf[2 * c + 1] * b2f((u16)(u >> 16));
    }
    d += __shfl_xor(d, 1);
    d += __shfl_xor(d, 2);
    d += __shfl_xor(d, 4);
    d += __shfl_xor(d, 8);
    lg[j] = d * 0.08838834764831845f;  // 128^-0.5
  }
  float mx = lg[0];
#pragma unroll
  for (int j = 1; j < KNN; ++j) mx = fmaxf(mx, lg[j]);
  float ssum = 0.f;
#pragma unroll
  for (int j = 0; j < KNN; ++j) { lg[j] = __expf(lg[j] - mx); ssum += lg[j]; }
  float inv = 1.0f / ssum;

  float a[8] = {0, 0, 0, 0, 0, 0, 0, 0};
#pragma unroll
  for (int j = 0; j < KNN; ++j) {
    bf16x8 v8 = *(const bf16x8*)(vb + (size_t)ms[j] * 128 + s * 8);
    float w = lg[j];
#pragma unroll
    for (int c = 0; c < 4; ++c) {
      uint32_t u = ((const uint32_t*)&v8)[c];
      a[2 * c] += w * b2f((u16)(u & 0xffff));
      a[2 * c + 1] += w * b2f((u16)(u >> 16));
    }
  }
  uint32_t ow[4];
#pragma unroll
  for (int c = 0; c < 4; ++c)
    ow[c] = (uint32_t)f2b(a[2 * c] * inv) | ((uint32_t)f2b(a[2 * c + 1] * inv) << 16);
  *(uint32_t*)(agg + (size_t)n * 128 + s * 8 + 0) = ow[0];
  *(uint32_t*)(agg + (size_t)n * 128 + s * 8 + 2) = ow[1];
  *(uint32_t*)(agg + (size_t)n * 128 + s * 8 + 4) = ow[2];
  *(uint32_t*)(agg + (size_t)n * 128 + s * 8 + 6) = ow[3];
}

extern "C" void kernel_launch(void* const* d_in, const int* in_sizes, int n_in,
                              void* d_out, int out_size, void* d_ws, size_t ws_size,
                              hipStream_t stream) {
  (void)in_sizes; (void)n_in; (void)out_size; (void)ws_size;
  const float* feats = (const float*)d_in[0];
  const int*   nbr   = (const int*)d_in[1];
  const int*   knn   = (const int*)d_in[2];
  const float* W_in  = (const float*)d_in[3];
  const float* b_in  = (const float*)d_in[4];
  const float* W_c0  = (const float*)d_in[5];
  const float* b_c0  = (const float*)d_in[6];
  const float* W_c1  = (const float*)d_in[7];
  const float* b_c1  = (const float*)d_in[8];
  const float* Wq    = (const float*)d_in[9];
  const float* Wk    = (const float*)d_in[10];
  const float* Wv    = (const float*)d_in[11];
  const float* Wo    = (const float*)d_in[12];
  const float* bo    = (const float*)d_in[13];
  const float* Wa0   = (const float*)d_in[14];
  const float* ba0   = (const float*)d_in[15];
  const float* Wa1   = (const float*)d_in[16];
  const float* ba1   = (const float*)d_in[17];
  const float* Wa2   = (const float*)d_in[18];
  const float* ba2   = (const float*)d_in[19];
  const float* Wb0   = (const float*)d_in[20];
  const float* bb0   = (const float*)d_in[21];
  const float* Wb1   = (const float*)d_in[22];
  const float* bb1   = (const float*)d_in[23];
  const float* W_out = (const float*)d_in[24];
  const float* b_out = (const float*)d_in[25];

  char* ws = (char*)d_ws;
  size_t off = 0;
  auto alloc = [&](size_t bytes) { size_t r = off; off += (bytes + 255) & ~(size_t)255; return r; };

  u16* wt_c0  = (u16*)(ws + alloc((size_t)81 * 16384 * 2));
  u16* wt_c1  = (u16*)(ws + alloc((size_t)81 * 16384 * 2));
  u16* wt_qkv = (u16*)(ws + alloc((size_t)9 * 16384 * 2));   // per stage: q,k,v slabs
  u16* wt_o   = (u16*)(ws + alloc((size_t)3 * 16384 * 2));
  u16* wt_a0  = (u16*)(ws + alloc((size_t)3 * 128 * 32 * 2));
  u16* wt_a1  = (u16*)(ws + alloc((size_t)81 * 32 * 32 * 2));
  u16* wt_a2  = (u16*)(ws + alloc((size_t)3 * 32 * 64 * 2));
  u16* wt_b0  = (u16*)(ws + alloc((size_t)81 * 128 * 32 * 2));
  u16* wt_b1  = (u16*)(ws + alloc((size_t)81 * 32 * 64 * 2));
  u16* wt_out = (u16*)(ws + alloc((size_t)27 * 16384 * 2));
  u16* wt_in  = (u16*)(ws + alloc((size_t)128 * 32 * 2));
  int* idx_t  = (int*)(ws + alloc((size_t)NK27 * NPTS * 4));
  u16* G27    = (u16*)(ws + alloc((size_t)NPTS * 32 * 2));

  u16* B0 = (u16*)(ws + alloc((size_t)(NPTS + 1) * 128 * 2));
  u16* B1 = (u16*)(ws + alloc((size_t)NPTS * 128 * 2));
  u16* KB = (u16*)(ws + alloc((size_t)(NPTS + 1) * 128 * 2));
  u16* VB = (u16*)(ws + alloc((size_t)(NPTS + 1) * 128 * 2));
  u16* QB = (u16*)(ws + alloc((size_t)NPTS * 128 * 2));
  u16* H1 = (u16*)(ws + alloc((size_t)(NPTS + 1) * 32 * 2));
  u16* HA = (u16*)(ws + alloc((size_t)NPTS * 32 * 2));
  u16* G  = (u16*)(ws + alloc((size_t)(NPTS + 1) * 32 * 2));
  u16* AGG = B0;
  u16* B2 = KB;
  u16* B3 = VB;

  auto TG = [](int tot) { return (tot + 255) / 256; };
  wtrans<<<TG(81 * 16384), 256, 0, stream>>>(W_c0, wt_c0, 81, 128, 128);
  wtrans<<<TG(81 * 16384), 256, 0, stream>>>(W_c1, wt_c1, 81, 128, 128);
  // qkv packed per stage: [s][{q,k,v}]
  wtrans<<<TG(16384), 256, 0, stream>>>(Wq + 0 * 16384, wt_qkv + (size_t)0 * 16384, 1, 128, 128);
  wtrans<<<TG(16384), 256, 0, stream>>>(Wk + 0 * 16384, wt_qkv + (size_t)1 * 16384, 1, 128, 128);
  wtrans<<<TG(16384), 256, 0, stream>>>(Wv + 0 * 16384, wt_qkv + (size_t)2 * 16384, 1, 128, 128);
  wtrans<<<TG(16384), 256, 0, stream>>>(Wq + 1 * 16384, wt_qkv + (size_t)3 * 16384, 1, 128, 128);
  wtrans<<<TG(16384), 256, 0, stream>>>(Wk + 1 * 16384, wt_qkv + (size_t)4 * 16384, 1, 128, 128);
  wtrans<<<TG(16384), 256, 0, stream>>>(Wv + 1 * 16384, wt_qkv + (size_t)5 * 16384, 1, 128, 128);
  wtrans<<<TG(16384), 256, 0, stream>>>(Wq + 2 * 16384, wt_qkv + (size_t)6 * 16384, 1, 128, 128);
  wtrans<<<TG(16384), 256, 0, stream>>>(Wk + 2 * 16384, wt_qkv + (size_t)7 * 16384, 1, 128, 128);
  wtrans<<<TG(16384), 256, 0, stream>>>(Wv + 2 * 16384, wt_qkv + (size_t)8 * 16384, 1, 128, 128);
  wtrans<<<TG(3 * 16384), 256, 0, stream>>>(Wo, wt_o, 3, 128, 128);
  wtrans<<<TG(3 * 128 * 32), 256, 0, stream>>>(Wa0, wt_a0, 3, 128, 32);
  wtrans<<<TG(81 * 32 * 32), 256, 0, stream>>>(Wa1, wt_a1, 81, 32, 32);
  wtrans<<<TG(3 * 32 * 64), 256, 0, stream>>>(Wa2, wt_a2, 3, 32, 64);
  wtrans<<<TG(81 * 128 * 32), 256, 0, stream>>>(Wb0, wt_b0, 81, 128, 32);
  wtrans<<<TG(81 * 32 * 64), 256, 0, stream>>>(Wb1, wt_b1, 81, 32, 64);
  wtrans<<<TG(27 * 16384), 256, 0, stream>>>(W_out, wt_out, 27, 128, 128);
  wtrans_in<<<TG(128 * 32), 256, 0, stream>>>(W_in, wt_in);
  itrans<<<NK27 * NPTS / 256, 256, 0, stream>>>(nbr, idx_t);

  zero_pads<<<1, 256, 0, stream>>>(B0 + (size_t)NPTS * 128, KB + (size_t)NPTS * 128,
                                   VB + (size_t)NPTS * 128, H1 + (size_t)NPTS * 32,
                                   G + (size_t)NPTS * 32);

  g27<<<NPTS * 32 / 256, 256, 0, stream>>>(feats, nbr, G27);
  sconv<32, 128, 1, 0, false><<<NPTS / 256, 512, 0, stream>>>(G27, nullptr, wt_in, b_in, nullptr, 0, B0, 128);

  const int GB = NPTS / 256;
  for (int s = 0; s < 3; ++s) {
    const u16* wc0 = wt_c0 + (size_t)s * 27 * 16384;
    const u16* wc1 = wt_c1 + (size_t)s * 27 * 16384;
    const u16* wqkv = wt_qkv + (size_t)s * 3 * 16384;
    const u16* wos = wt_o + (size_t)s * 16384;
    const u16* wa0 = wt_a0 + (size_t)s * 4096;
    const u16* wa1 = wt_a1 + (size_t)s * 27648;
    const u16* wa2 = wt_a2 + (size_t)s * 2048;
    const u16* wb0 = wt_b0 + (size_t)s * 110592;
    const u16* wb1 = wt_b1 + (size_t)s * 55296;

    sconv<128, 128, 27, 0, false><<<GB, 512, 0, stream>>>(B0, idx_t, wc0, b_c0 + s * 128, nullptr, 0, B1, 128);
    qkv_k<<<GB, 512, 0, stream>>>(B1, wqkv, QB, KB, VB);
    attn_k<<<NPTS / 16, 256, 0, stream>>>(QB, KB, VB, knn, AGG);
    sconv<128, 128, 1, 2, false><<<GB, 512, 0, stream>>>(AGG, nullptr, wos, bo + s * 128, B1, 128, B2, 128);
    sconv<128, 128, 27, 0, false><<<GB, 512, 0, stream>>>(B2, idx_t, wc1, b_c1 + s * 128, nullptr, 0, B3, 128);
    sconv<128, 32, 1, 1, false><<<GB, 512, 0, stream>>>(B3, nullptr, wa0, ba0 + s * 32, nullptr, 0, H1, 32);
    sconv<32, 32, 27, 1, false><<<GB, 512, 0, stream>>>(H1, idx_t, wa1, ba1 + s * 32, nullptr, 0, HA, 32);
    sconv<32, 64, 1, 3, false><<<GB, 512, 0, stream>>>(HA, idx_t, wa2, ba2 + s * 64, B3, 128, B0, 128);
    sconv<128, 32, 27, 1, false><<<GB, 512, 0, stream>>>(B3, idx_t, wb0, bb0 + s * 32, nullptr, 0, G, 32);
    sconv<32, 64, 27, 3, false><<<GB, 512, 0, stream>>>(G, idx_t, wb1, bb1 + s * 64, B3 + 64, 128, (void*)(B0 + 64), 128);
  }
  sconv<128, 128, 27, 0, true><<<GB, 512, 0, stream>>>(B0, idx_t, wt_out, b_out, nullptr, 0, d_out, 128);
}

// Round 8
// 1181.993 us; speedup vs baseline: 1.4138x; 1.0190x over previous
//
#include <hip/hip_runtime.h>
#include <stdint.h>

typedef unsigned short u16;
typedef __attribute__((ext_vector_type(8))) short bf16x8;
typedef __attribute__((ext_vector_type(4))) float f32x4;

#define NPTS 65536
#define NK27 27
#define KNN 16

__device__ __forceinline__ u16 f2b(float f) {
  union { float f; uint32_t u; } v; v.f = f;
  uint32_t r = (v.u + 0x7fffu + ((v.u >> 16) & 1u)) >> 16;
  return (u16)r;
}
__device__ __forceinline__ float b2f(u16 h) {
  union { uint32_t u; float f; } v; v.u = ((uint32_t)h) << 16; return v.f;
}

// wait until <=N VMEM ops outstanding (ignore lgkm/exp). gfx9 encoding.
template<int N>
__device__ __forceinline__ void waitcnt_vm() {
  __builtin_amdgcn_s_waitcnt((N & 0xF) | ((N >> 4) << 14) | (0x7 << 4) | (0xF << 8));
}

// dst[g][co][swz(ci)] (bf16) = src[g][ci][co] (f32); id is dst-linear.
__global__ __launch_bounds__(256) void wtrans(const float* __restrict__ src, u16* __restrict__ dst,
                                              int G, int CI, int CO) {
  int id = blockIdx.x * 256 + threadIdx.x;
  int tot = G * CI * CO;
  if (id >= tot) return;
  int cpr = CI / 8;
  int swzb = (cpr < 8 ? cpr : 8) - 1;
  int g = id / (CI * CO);
  int r = id - g * (CI * CO);
  int co = r / CI;
  int cis = r - co * CI;
  int c = cis / 8, e = cis - c * 8;
  int ci = (c ^ (co & swzb)) * 8 + e;
  dst[id] = f2b(src[(size_t)g * CI * CO + (size_t)ci * CO + co]);
}

// W_in: [27][1][128] f32 -> dst[co][k32] bf16 (k padded 27->32, swizzled, CPR=4)
__global__ __launch_bounds__(256) void wtrans_in(const float* __restrict__ W, u16* __restrict__ dst) {
  int id = blockIdx.x * 256 + threadIdx.x;
  if (id >= 128 * 32) return;
  int co = id >> 5, cis = id & 31;
  int c = cis >> 3, e = cis & 7;
  int ci = ((c ^ (co & 3)) << 3) | e;
  dst[id] = (ci < NK27) ? f2b(W[ci * 128 + co]) : (u16)0;
}

// G[n][32] bf16 = gathered feats (k<27, idx<NPTS), else 0
__global__ __launch_bounds__(256) void g27(const float* __restrict__ feats, const int* __restrict__ nbr,
                                           u16* __restrict__ G) {
  int id = blockIdx.x * 256 + threadIdx.x;
  int n = id >> 5, j = id & 31;
  u16 v = 0;
  if (j < NK27) {
    int m = nbr[n * NK27 + j];
    if (m < NPTS) v = f2b(feats[m]);
  }
  G[id] = v;
}

// idx transpose: out[k][n] = nbr[n][k]
__global__ __launch_bounds__(256) void itrans(const int* __restrict__ nbr, int* __restrict__ out) {
  int id = blockIdx.x * 256 + threadIdx.x;
  int k = id >> 16;
  int n = id & (NPTS - 1);
  out[id] = nbr[n * NK27 + k];
}

__global__ void zero_pads(u16* a, u16* b, u16* c, u16* d, u16* e) {
  int t = threadIdx.x;
  if (t < 128) { a[t] = 0; b[t] = 0; c[t] = 0; }
  if (t < 32) { d[t] = 0; e[t] = 0; }
}

#define GLDS16(g, l)                                                                        \
  __builtin_amdgcn_global_load_lds((const __attribute__((address_space(1))) void*)(g),      \
                                   (__attribute__((address_space(3))) void*)(l), 16, 0, 0)

// Gathered GEMM, BM=256, 8 waves, wave tile 32xCOUT (no A duplication).
// 2-tap periods: one barrier per TWO taps; 4 LDS slabs; 3 rotating A-reg sets;
// every gather gets ~2 compute phases to land. Counted-vmcnt entries.
// EMODE: 0=none 1=relu(v) 2=relu(v+res) 3=relu(v)+res
template<int CIN, int COUT, int NK, int EMODE, bool OUTF32>
__global__ __launch_bounds__(512, 2)
void sconv(const u16* __restrict__ x, const int* __restrict__ idxt,
           const u16* __restrict__ Wt, const float* __restrict__ bias,
           const u16* __restrict__ res, int res_stride,
           void* __restrict__ yout, int out_stride) {
  static_assert(NK == 1 || NK == 27, "NK 1 or 27");
  constexpr int BM = 256;
  constexpr int KK = CIN / 32;
  constexpr int CPR = CIN / 8;
  constexpr int SWZB = (CPR < 8 ? CPR : 8) - 1;
  constexpr int N_REP = COUT / 16;
  constexpr int M_REP = 2;
  constexpr int BSZ = COUT * CIN;
  constexpr int BCH = BSZ / 8;
  constexpr int BISS = (BCH + 511) / 512;
  constexpr int AC = M_REP * KK;       // A vmem ops per tap per wave
  constexpr int IC = 2 * M_REP;        // idx ops per pair per wave
  constexpr int VC_E = 2 * AC + IC;    // generic period entry
  constexpr int VC_L = AC;             // final-tap entry
  constexpr int NSLAB = (NK > 1) ? 4 : 1;

  __shared__ __attribute__((aligned(16))) u16 Bs[NSLAB][BSZ];

  const int tid = threadIdx.x;
  const int lane = tid & 63;
  const int wave = tid >> 6;
  const int n0 = blockIdx.x * BM;
  const int lr = lane & 15;
  const int lh = lane >> 4;
  const int row0 = wave * 32;

  f32x4 acc[M_REP][N_REP];
#pragma unroll
  for (int i = 0; i < M_REP; ++i)
#pragma unroll
    for (int j = 0; j < N_REP; ++j) acc[i][j] = (f32x4){0.f, 0.f, 0.f, 0.f};

  bf16x8 S0[M_REP][KK], S1[M_REP][KK], S2[M_REP][KK];
  int I0[2][M_REP], I1[2][M_REP];

  auto stage1 = [&](int k, int slab) {
    const u16* src = Wt + (size_t)k * BSZ;
    u16* dst = &Bs[(NK > 1) ? slab : 0][0];
#pragma unroll
    for (int i = 0; i < BISS; ++i) {
      int cb = i * 512 + wave * 64;
      if (BCH % 512 == 0 || cb < BCH)
        GLDS16(src + (size_t)(cb + lane) * 8, dst + (size_t)cb * 8);
    }
  };
  auto loadIdxPair = [&](int p, int (&m)[2][M_REP]) {
#pragma unroll
    for (int t = 0; t < 2; ++t)
#pragma unroll
      for (int mr = 0; mr < M_REP; ++mr)
        m[t][mr] = idxt[(size_t)(2 * p + t) * NPTS + n0 + row0 + mr * 16 + lr];
  };
  auto issueA = [&](const int (&m)[M_REP], bf16x8 (&dst)[M_REP][KK]) {
#pragma unroll
    for (int mr = 0; mr < M_REP; ++mr)
#pragma unroll
      for (int kk = 0; kk < KK; ++kk)
        dst[mr][kk] = *(const bf16x8*)(x + (size_t)m[mr] * CIN + kk * 32 + lh * 8);
  };
  auto compute = [&](int slab, const bf16x8 (&AR)[M_REP][KK]) {
    const u16* bsp = &Bs[(NK > 1) ? slab : 0][0];
#pragma unroll
    for (int kk = 0; kk < KK; ++kk) {
      bf16x8 b[N_REP];
      int pc = (kk * 4 + lh) ^ (lr & SWZB);
#pragma unroll
      for (int nr = 0; nr < N_REP; ++nr)
        b[nr] = *(const bf16x8*)(bsp + (size_t)(nr * 16 + lr) * CIN + pc * 8);
#pragma unroll
      for (int mr = 0; mr < M_REP; ++mr)
#pragma unroll
        for (int nr = 0; nr < N_REP; ++nr)
          acc[mr][nr] = __builtin_amdgcn_mfma_f32_16x16x32_bf16(AR[mr][kk], b[nr], acc[mr][nr], 0, 0, 0);
    }
  };

#define SBAR __builtin_amdgcn_sched_barrier(0)

  if constexpr (NK == 1) {
    int m0[M_REP];
#pragma unroll
    for (int mr = 0; mr < M_REP; ++mr) m0[mr] = n0 + row0 + mr * 16 + lr;
    stage1(0, 0);
    issueA(m0, S0);
    __syncthreads();
    compute(0, S0);
  } else {
    // prologue: idxP(0); stage taps 0,1; A(0)->S0; A(1)->S1; idxP(1)
    loadIdxPair(0, I0);
    SBAR;
    stage1(0, 0); stage1(1, 1);
    SBAR;
    issueA(I0[0], S0);
    SBAR;
    issueA(I0[1], S1);
    SBAR;
    loadIdxPair(1, I1);
    SBAR;

// period p: compute taps (2p,2p+1) from sets (SA,SB) @ slabs (C0,C1);
// stage pair p+1 -> slabs (N0,N1); A(2p+2)->SC, A(2p+3)->SA; idxP(p+2)->IW.
#define PERX(p, SA, SB, SC, IU, IW, C0, C1, N0, N1)                           \
    waitcnt_vm<VC_E>();                                                       \
    __builtin_amdgcn_s_barrier();                                             \
    SBAR;                                                                     \
    stage1(2 * (p) + 2, N0);                                                  \
    stage1(2 * (p) + 3, N1);                                                  \
    SBAR;                                                                     \
    issueA(IU[0], SC);                                                        \
    SBAR;                                                                     \
    loadIdxPair((p) + 2, IW);                                                 \
    SBAR;                                                                     \
    compute(C0, SA);                                                          \
    SBAR;                                                                     \
    issueA(IU[1], SA);                                                        \
    SBAR;                                                                     \
    compute(C1, SB);                                                          \
    SBAR;

#define SIXP(pb)                                                              \
    PERX(pb + 0, S0, S1, S2, I1, I0, 0, 1, 2, 3)                              \
    PERX(pb + 1, S2, S0, S1, I0, I1, 2, 3, 0, 1)                              \
    PERX(pb + 2, S1, S2, S0, I1, I0, 0, 1, 2, 3)                              \
    PERX(pb + 3, S0, S1, S2, I0, I1, 2, 3, 0, 1)                              \
    PERX(pb + 4, S2, S0, S1, I1, I0, 0, 1, 2, 3)                              \
    PERX(pb + 5, S1, S2, S0, I0, I1, 2, 3, 0, 1)

    SIXP(0)
    SIXP(6)
    // p = 12 (taps 24,25): stage tap 26 only; A(26)->S2; no idx, no A(27)
    waitcnt_vm<VC_E>();
    __builtin_amdgcn_s_barrier();
    SBAR;
    stage1(26, 2);
    SBAR;
    issueA(I1[0], S2);
    SBAR;
    compute(0, S0);
    SBAR;
    compute(1, S1);
    SBAR;
    // final tap 26
    waitcnt_vm<VC_L>();
    __builtin_amdgcn_s_barrier();
    SBAR;
    compute(2, S2);
#undef SIXP
#undef PERX
  }
#undef SBAR

#pragma unroll
  for (int mr = 0; mr < M_REP; ++mr) {
#pragma unroll
    for (int nr = 0; nr < N_REP; ++nr) {
      int col = nr * 16 + lr;
      float bv = bias ? bias[col] : 0.0f;
#pragma unroll
      for (int j = 0; j < 4; ++j) {
        int n = n0 + row0 + mr * 16 + lh * 4 + j;
        float v = acc[mr][nr][j] + bv;
        if (EMODE == 1) v = fmaxf(v, 0.0f);
        else if (EMODE == 2) v = fmaxf(v + b2f(res[(size_t)n * res_stride + col]), 0.0f);
        else if (EMODE == 3) v = fmaxf(v, 0.0f) + b2f(res[(size_t)n * res_stride + col]);
        if (OUTF32) ((float*)yout)[(size_t)n * out_stride + col] = v;
        else ((u16*)yout)[(size_t)n * out_stride + col] = f2b(v);
      }
    }
  }
}

// Fused q/k/v projections: A rows loaded to regs ONCE, 3 weight slabs staged
// through one LDS buffer sequentially. x: [NPTS][128]; Wt: 3 slabs of [128][128].
__global__ __launch_bounds__(512, 2)
void qkv_k(const u16* __restrict__ x, const u16* __restrict__ Wt,
           u16* __restrict__ qo, u16* __restrict__ ko, u16* __restrict__ vo) {
  constexpr int CIN = 128, COUT = 128;
  constexpr int KK = 4, SWZB = 7, N_REP = 8, M_REP = 2;
  constexpr int BSZ = COUT * CIN;
  constexpr int BISS = (BSZ / 8) / 512;

  __shared__ __attribute__((aligned(16))) u16 Bs[BSZ];

  const int tid = threadIdx.x;
  const int lane = tid & 63;
  const int wave = tid >> 6;
  const int n0 = blockIdx.x * 256;
  const int lr = lane & 15;
  const int lh = lane >> 4;
  const int row0 = wave * 32;

  bf16x8 A0[M_REP][KK];
#pragma unroll
  for (int mr = 0; mr < M_REP; ++mr)
#pragma unroll
    for (int kk = 0; kk < KK; ++kk)
      A0[mr][kk] = *(const bf16x8*)(x + (size_t)(n0 + row0 + mr * 16 + lr) * CIN + kk * 32 + lh * 8);

  u16* outs[3] = {qo, ko, vo};
  for (int w = 0; w < 3; ++w) {
    if (w) __syncthreads();
    const u16* src = Wt + (size_t)w * BSZ;
#pragma unroll
    for (int i = 0; i < BISS; ++i) {
      int cb = i * 512 + wave * 64;
      GLDS16(src + (size_t)(cb + lane) * 8, &Bs[(size_t)cb * 8]);
    }
    __syncthreads();

    f32x4 acc[M_REP][N_REP];
#pragma unroll
    for (int i = 0; i < M_REP; ++i)
#pragma unroll
      for (int j = 0; j < N_REP; ++j) acc[i][j] = (f32x4){0.f, 0.f, 0.f, 0.f};
#pragma unroll
    for (int kk = 0; kk < KK; ++kk) {
      bf16x8 b[N_REP];
      int pc = (kk * 4 + lh) ^ (lr & SWZB);
#pragma unroll
      for (int nr = 0; nr < N_REP; ++nr)
        b[nr] = *(const bf16x8*)(&Bs[(size_t)(nr * 16 + lr) * CIN + pc * 8]);
#pragma unroll
      for (int mr = 0; mr < M_REP; ++mr)
#pragma unroll
        for (int nr = 0; nr < N_REP; ++nr)
          acc[mr][nr] = __builtin_amdgcn_mfma_f32_16x16x32_bf16(A0[mr][kk], b[nr], acc[mr][nr], 0, 0, 0);
    }
    u16* yo = outs[w];
#pragma unroll
    for (int mr = 0; mr < M_REP; ++mr)
#pragma unroll
      for (int nr = 0; nr < N_REP; ++nr) {
        int col = nr * 16 + lr;
#pragma unroll
        for (int j = 0; j < 4; ++j) {
          int n = n0 + row0 + mr * 16 + lh * 4 + j;
          yo[(size_t)n * 128 + col] = f2b(acc[mr][nr][j]);
        }
      }
  }
}

// kNN attention: 16 lanes per point, 4 points per wave.
__global__ __launch_bounds__(256)
void attn_k(const u16* __restrict__ qb, const u16* __restrict__ kb,
            const u16* __restrict__ vb, const int* __restrict__ knn,
            u16* __restrict__ agg) {
  const int t = blockIdx.x * 256 + threadIdx.x;
  const int n = t >> 4;
  const int s = t & 15;
  const int lane = threadIdx.x & 63;
  const int gbase = lane & 48;

  int myidx = knn[n * KNN + s];

  bf16x8 q8 = *(const bf16x8*)(qb + (size_t)n * 128 + s * 8);
  float qf[8];
#pragma unroll
  for (int c = 0; c < 4; ++c) {
    uint32_t u = ((const uint32_t*)&q8)[c];
    qf[2 * c] = b2f((u16)(u & 0xffff));
    qf[2 * c + 1] = b2f((u16)(u >> 16));
  }

  float lg[KNN];
  int ms[KNN];
#pragma unroll
  for (int j = 0; j < KNN; ++j) {
    int mj = __shfl(myidx, gbase | j);
    ms[j] = mj;
    bf16x8 k8 = *(const bf16x8*)(kb + (size_t)mj * 128 + s * 8);
    float d = 0.f;
#pragma unroll
    for (int c = 0; c < 4; ++c) {
      uint32_t u = ((const uint32_t*)&k8)[c];
      d += qf[2 * c] * b2f((u16)(u & 0xffff));
      d += qf[2 * c + 1] * b2f((u16)(u >> 16));
    }
    d += __shfl_xor(d, 1);
    d += __shfl_xor(d, 2);
    d += __shfl_xor(d, 4);
    d += __shfl_xor(d, 8);
    lg[j] = d * 0.08838834764831845f;
  }
  float mx = lg[0];
#pragma unroll
  for (int j = 1; j < KNN; ++j) mx = fmaxf(mx, lg[j]);
  float ssum = 0.f;
#pragma unroll
  for (int j = 0; j < KNN; ++j) { lg[j] = __expf(lg[j] - mx); ssum += lg[j]; }
  float inv = 1.0f / ssum;

  float a[8] = {0, 0, 0, 0, 0, 0, 0, 0};
#pragma unroll
  for (int j = 0; j < KNN; ++j) {
    bf16x8 v8 = *(const bf16x8*)(vb + (size_t)ms[j] * 128 + s * 8);
    float w = lg[j];
#pragma unroll
    for (int c = 0; c < 4; ++c) {
      uint32_t u = ((const uint32_t*)&v8)[c];
      a[2 * c] += w * b2f((u16)(u & 0xffff));
      a[2 * c + 1] += w * b2f((u16)(u >> 16));
    }
  }
  uint32_t ow[4];
#pragma unroll
  for (int c = 0; c < 4; ++c)
    ow[c] = (uint32_t)f2b(a[2 * c] * inv) | ((uint32_t)f2b(a[2 * c + 1] * inv) << 16);
  *(uint32_t*)(agg + (size_t)n * 128 + s * 8 + 0) = ow[0];
  *(uint32_t*)(agg + (size_t)n * 128 + s * 8 + 2) = ow[1];
  *(uint32_t*)(agg + (size_t)n * 128 + s * 8 + 4) = ow[2];
  *(uint32_t*)(agg + (size_t)n * 128 + s * 8 + 6) = ow[3];
}

extern "C" void kernel_launch(void* const* d_in, const int* in_sizes, int n_in,
                              void* d_out, int out_size, void* d_ws, size_t ws_size,
                              hipStream_t stream) {
  (void)in_sizes; (void)n_in; (void)out_size; (void)ws_size;
  const float* feats = (const float*)d_in[0];
  const int*   nbr   = (const int*)d_in[1];
  const int*   knn   = (const int*)d_in[2];
  const float* W_in  = (const float*)d_in[3];
  const float* b_in  = (const float*)d_in[4];
  const float* W_c0  = (const float*)d_in[5];
  const float* b_c0  = (const float*)d_in[6];
  const float* W_c1  = (const float*)d_in[7];
  const float* b_c1  = (const float*)d_in[8];
  const float* Wq    = (const float*)d_in[9];
  const float* Wk    = (const float*)d_in[10];
  const float* Wv    = (const float*)d_in[11];
  const float* Wo    = (const float*)d_in[12];
  const float* bo    = (const float*)d_in[13];
  const float* Wa0   = (const float*)d_in[14];
  const float* ba0   = (const float*)d_in[15];
  const float* Wa1   = (const float*)d_in[16];
  const float* ba1   = (const float*)d_in[17];
  const float* Wa2   = (const float*)d_in[18];
  const float* ba2   = (const float*)d_in[19];
  const float* Wb0   = (const float*)d_in[20];
  const float* bb0   = (const float*)d_in[21];
  const float* Wb1   = (const float*)d_in[22];
  const float* bb1   = (const float*)d_in[23];
  const float* W_out = (const float*)d_in[24];
  const float* b_out = (const float*)d_in[25];

  char* ws = (char*)d_ws;
  size_t off = 0;
  auto alloc = [&](size_t bytes) { size_t r = off; off += (bytes + 255) & ~(size_t)255; return r; };

  u16* wt_c0  = (u16*)(ws + alloc((size_t)81 * 16384 * 2));
  u16* wt_c1  = (u16*)(ws + alloc((size_t)81 * 16384 * 2));
  u16* wt_qkv = (u16*)(ws + alloc((size_t)9 * 16384 * 2));
  u16* wt_o   = (u16*)(ws + alloc((size_t)3 * 16384 * 2));
  u16* wt_a0  = (u16*)(ws + alloc((size_t)3 * 128 * 32 * 2));
  u16* wt_a1  = (u16*)(ws + alloc((size_t)81 * 32 * 32 * 2));
  u16* wt_a2  = (u16*)(ws + alloc((size_t)3 * 32 * 64 * 2));
  u16* wt_b0  = (u16*)(ws + alloc((size_t)81 * 128 * 32 * 2));
  u16* wt_b1  = (u16*)(ws + alloc((size_t)81 * 32 * 64 * 2));
  u16* wt_out = (u16*)(ws + alloc((size_t)27 * 16384 * 2));
  u16* wt_in  = (u16*)(ws + alloc((size_t)128 * 32 * 2));
  int* idx_t  = (int*)(ws + alloc((size_t)(NK27 + 1) * NPTS * 4));  // +1 row: pair-tail overread
  u16* G27    = (u16*)(ws + alloc((size_t)NPTS * 32 * 2));

  u16* B0 = (u16*)(ws + alloc((size_t)(NPTS + 1) * 128 * 2));
  u16* B1 = (u16*)(ws + alloc((size_t)NPTS * 128 * 2));
  u16* KB = (u16*)(ws + alloc((size_t)(NPTS + 1) * 128 * 2));
  u16* VB = (u16*)(ws + alloc((size_t)(NPTS + 1) * 128 * 2));
  u16* QB = (u16*)(ws + alloc((size_t)NPTS * 128 * 2));
  u16* H1 = (u16*)(ws + alloc((size_t)(NPTS + 1) * 32 * 2));
  u16* HA = (u16*)(ws + alloc((size_t)NPTS * 32 * 2));
  u16* G  = (u16*)(ws + alloc((size_t)(NPTS + 1) * 32 * 2));
  u16* AGG = B0;
  u16* B2 = KB;
  u16* B3 = VB;

  auto TG = [](int tot) { return (tot + 255) / 256; };
  wtrans<<<TG(81 * 16384), 256, 0, stream>>>(W_c0, wt_c0, 81, 128, 128);
  wtrans<<<TG(81 * 16384), 256, 0, stream>>>(W_c1, wt_c1, 81, 128, 128);
  wtrans<<<TG(16384), 256, 0, stream>>>(Wq + 0 * 16384, wt_qkv + (size_t)0 * 16384, 1, 128, 128);
  wtrans<<<TG(16384), 256, 0, stream>>>(Wk + 0 * 16384, wt_qkv + (size_t)1 * 16384, 1, 128, 128);
  wtrans<<<TG(16384), 256, 0, stream>>>(Wv + 0 * 16384, wt_qkv + (size_t)2 * 16384, 1, 128, 128);
  wtrans<<<TG(16384), 256, 0, stream>>>(Wq + 1 * 16384, wt_qkv + (size_t)3 * 16384, 1, 128, 128);
  wtrans<<<TG(16384), 256, 0, stream>>>(Wk + 1 * 16384, wt_qkv + (size_t)4 * 16384, 1, 128, 128);
  wtrans<<<TG(16384), 256, 0, stream>>>(Wv + 1 * 16384, wt_qkv + (size_t)5 * 16384, 1, 128, 128);
  wtrans<<<TG(16384), 256, 0, stream>>>(Wq + 2 * 16384, wt_qkv + (size_t)6 * 16384, 1, 128, 128);
  wtrans<<<TG(16384), 256, 0, stream>>>(Wk + 2 * 16384, wt_qkv + (size_t)7 * 16384, 1, 128, 128);
  wtrans<<<TG(16384), 256, 0, stream>>>(Wv + 2 * 16384, wt_qkv + (size_t)8 * 16384, 1, 128, 128);
  wtrans<<<TG(3 * 16384), 256, 0, stream>>>(Wo, wt_o, 3, 128, 128);
  wtrans<<<TG(3 * 128 * 32), 256, 0, stream>>>(Wa0, wt_a0, 3, 128, 32);
  wtrans<<<TG(81 * 32 * 32), 256, 0, stream>>>(Wa1, wt_a1, 81, 32, 32);
  wtrans<<<TG(3 * 32 * 64), 256, 0, stream>>>(Wa2, wt_a2, 3, 32, 64);
  wtrans<<<TG(81 * 128 * 32), 256, 0, stream>>>(Wb0, wt_b0, 81, 128, 32);
  wtrans<<<TG(81 * 32 * 64), 256, 0, stream>>>(Wb1, wt_b1, 81, 32, 64);
  wtrans<<<TG(27 * 16384), 256, 0, stream>>>(W_out, wt_out, 27, 128, 128);
  wtrans_in<<<TG(128 * 32), 256, 0, stream>>>(W_in, wt_in);
  itrans<<<NK27 * NPTS / 256, 256, 0, stream>>>(nbr, idx_t);

  zero_pads<<<1, 256, 0, stream>>>(B0 + (size_t)NPTS * 128, KB + (size_t)NPTS * 128,
                                   VB + (size_t)NPTS * 128, H1 + (size_t)NPTS * 32,
                                   G + (size_t)NPTS * 32);

  g27<<<NPTS * 32 / 256, 256, 0, stream>>>(feats, nbr, G27);
  sconv<32, 128, 1, 0, false><<<NPTS / 256, 512, 0, stream>>>(G27, nullptr, wt_in, b_in, nullptr, 0, B0, 128);

  const int GB = NPTS / 256;
  for (int s = 0; s < 3; ++s) {
    const u16* wc0 = wt_c0 + (size_t)s * 27 * 16384;
    const u16* wc1 = wt_c1 + (size_t)s * 27 * 16384;
    const u16* wqkv = wt_qkv + (size_t)s * 3 * 16384;
    const u16* wos = wt_o + (size_t)s * 16384;
    const u16* wa0 = wt_a0 + (size_t)s * 4096;
    const u16* wa1 = wt_a1 + (size_t)s * 27648;
    const u16* wa2 = wt_a2 + (size_t)s * 2048;
    const u16* wb0 = wt_b0 + (size_t)s * 110592;
    const u16* wb1 = wt_b1 + (size_t)s * 55296;

    sconv<128, 128, 27, 0, false><<<GB, 512, 0, stream>>>(B0, idx_t, wc0, b_c0 + s * 128, nullptr, 0, B1, 128);
    qkv_k<<<GB, 512, 0, stream>>>(B1, wqkv, QB, KB, VB);
    attn_k<<<NPTS / 16, 256, 0, stream>>>(QB, KB, VB, knn, AGG);
    sconv<128, 128, 1, 2, false><<<GB, 512, 0, stream>>>(AGG, nullptr, wos, bo + s * 128, B1, 128, B2, 128);
    sconv<128, 128, 27, 0, false><<<GB, 512, 0, stream>>>(B2, idx_t, wc1, b_c1 + s * 128, nullptr, 0, B3, 128);
    sconv<128, 32, 1, 1, false><<<GB, 512, 0, stream>>>(B3, nullptr, wa0, ba0 + s * 32, nullptr, 0, H1, 32);
    sconv<32, 32, 27, 1, false><<<GB, 512, 0, stream>>>(H1, idx_t, wa1, ba1 + s * 32, nullptr, 0, HA, 32);
    sconv<32, 64, 1, 3, false><<<GB, 512, 0, stream>>>(HA, idx_t, wa2, ba2 + s * 64, B3, 128, B0, 128);
    sconv<128, 32, 27, 1, false><<<GB, 512, 0, stream>>>(B3, idx_t, wb0, bb0 + s * 32, nullptr, 0, G, 32);
    sconv<32, 64, 27, 3, false><<<GB, 512, 0, stream>>>(G, idx_t, wb1, bb1 + s * 64, B3 + 64, 128, (void*)(B0 + 64), 128);
  }
  sconv<128, 128, 27, 0, true><<<GB, 512, 0, stream>>>(B0, idx_t, wt_out, b_out, nullptr, 0, d_out, 128);
}

// Round 9
// 1153.920 us; speedup vs baseline: 1.4482x; 1.0243x over previous
//
#include <hip/hip_runtime.h>
#include <stdint.h>

typedef unsigned short u16;
typedef __attribute__((ext_vector_type(8))) short bf16x8;
typedef __attribute__((ext_vector_type(4))) float f32x4;

#define NPTS 65536
#define NK27 27
#define KNN 16

__device__ __forceinline__ u16 f2b(float f) {
  union { float f; uint32_t u; } v; v.f = f;
  uint32_t r = (v.u + 0x7fffu + ((v.u >> 16) & 1u)) >> 16;
  return (u16)r;
}
__device__ __forceinline__ float b2f(u16 h) {
  union { uint32_t u; float f; } v; v.u = ((uint32_t)h) << 16; return v.f;
}

// wait until <=N VMEM ops outstanding (ignore lgkm/exp). gfx9 encoding.
template<int N>
__device__ __forceinline__ void waitcnt_vm() {
  __builtin_amdgcn_s_waitcnt((N & 0xF) | ((N >> 4) << 14) | (0x7 << 4) | (0xF << 8));
}

// Tiled weight transpose: src [G][CI][CO] f32 -> dst[g*dstride + co*CI + swz(ci)] bf16.
// Coalesced f32 reads (over co), LDS 32x33 transpose, 16B-chunk swizzled writes.
__global__ __launch_bounds__(256)
void wtrans_t(const float* __restrict__ src, u16* __restrict__ dst,
              int CI, int CO, int dstride) {
  int tiles_ci = CI >> 5;
  int g = blockIdx.y;
  int tci = (blockIdx.x % tiles_ci) << 5;
  int tco = (blockIdx.x / tiles_ci) << 5;
  __shared__ float T[32][33];
  int t = threadIdx.x;
  int r = t >> 5, c = t & 31;
  const float* sp = src + (size_t)g * CI * CO;
#pragma unroll
  for (int i = 0; i < 4; ++i)
    T[r + i * 8][c] = sp[(size_t)(tci + r + i * 8) * CO + tco + c];
  __syncthreads();
  int swzb = ((CI >> 3) < 8 ? (CI >> 3) : 8) - 1;
  u16* dp = dst + (size_t)g * dstride;
#pragma unroll
  for (int i = 0; i < 4; ++i) {
    int co = tco + r + i * 8;
    int ci = tci + c;                 // source ci held in T[c][r+i*8]
    int ch = ci >> 3, e = ci & 7;
    int chs = ch ^ (co & swzb);       // swizzled 16B-chunk position
    dp[(size_t)co * CI + chs * 8 + e] = f2b(T[c][r + i * 8]);
  }
}

// W_in: [27][1][128] f32 -> dst[co][k32] bf16 (k padded 27->32, swizzled, CPR=4)
__global__ __launch_bounds__(256) void wtrans_in(const float* __restrict__ W, u16* __restrict__ dst) {
  int id = blockIdx.x * 256 + threadIdx.x;
  if (id >= 128 * 32) return;
  int co = id >> 5, cis = id & 31;
  int c = cis >> 3, e = cis & 7;
  int ci = ((c ^ (co & 3)) << 3) | e;
  dst[id] = (ci < NK27) ? f2b(W[ci * 128 + co]) : (u16)0;
}

// G[n][32] bf16 = gathered feats (k<27, idx<NPTS), else 0
__global__ __launch_bounds__(256) void g27(const float* __restrict__ feats, const int* __restrict__ nbr,
                                           u16* __restrict__ G) {
  int id = blockIdx.x * 256 + threadIdx.x;
  int n = id >> 5, j = id & 31;
  u16 v = 0;
  if (j < NK27) {
    int m = nbr[n * NK27 + j];
    if (m < NPTS) v = f2b(feats[m]);
  }
  G[id] = v;
}

// Tiled idx transpose: nbr [N][27] -> out[k][n]. Coalesced reads and writes.
__global__ __launch_bounds__(256) void itrans_t(const int* __restrict__ nbr, int* __restrict__ out) {
  __shared__ int T[NK27 * 257];
  int n0 = blockIdx.x * 256;
  int t = threadIdx.x;
#pragma unroll
  for (int i = 0; i < NK27; ++i) {
    int id = i * 256 + t;
    int nl = id / NK27, k = id - nl * NK27;
    T[k * 257 + nl] = nbr[(size_t)n0 * NK27 + id];
  }
  __syncthreads();
#pragma unroll
  for (int k = 0; k < NK27; ++k)
    out[(size_t)k * NPTS + n0 + t] = T[k * 257 + t];
}

__global__ void zero_pads(u16* a, u16* b, u16* c, u16* d, u16* e) {
  int t = threadIdx.x;
  if (t < 128) { a[t] = 0; b[t] = 0; c[t] = 0; }
  if (t < 32) { d[t] = 0; e[t] = 0; }
}

#define GLDS16(g, l)                                                                        \
  __builtin_amdgcn_global_load_lds((const __attribute__((address_space(1))) void*)(g),      \
                                   (__attribute__((address_space(3))) void*)(l), 16, 0, 0)

// Gathered GEMM, BM=256, 8 waves, wave tile 32xCOUT (no A duplication).
// 2-tap periods: one barrier per TWO taps; 4 LDS slabs; 3 rotating A-reg sets.
// EMODE: 0=none 1=relu(v) 2=relu(v+res) 3=relu(v)+res
template<int CIN, int COUT, int NK, int EMODE, bool OUTF32>
__global__ __launch_bounds__(512, 2)
void sconv(const u16* __restrict__ x, const int* __restrict__ idxt,
           const u16* __restrict__ Wt, const float* __restrict__ bias,
           const u16* __restrict__ res, int res_stride,
           void* __restrict__ yout, int out_stride) {
  static_assert(NK == 1 || NK == 27, "NK 1 or 27");
  constexpr int BM = 256;
  constexpr int KK = CIN / 32;
  constexpr int CPR = CIN / 8;
  constexpr int SWZB = (CPR < 8 ? CPR : 8) - 1;
  constexpr int N_REP = COUT / 16;
  constexpr int M_REP = 2;
  constexpr int BSZ = COUT * CIN;
  constexpr int BCH = BSZ / 8;
  constexpr int BISS = (BCH + 511) / 512;
  constexpr int AC = M_REP * KK;       // A vmem ops per tap per wave
  constexpr int IC = 2 * M_REP;        // idx ops per pair per wave
  constexpr int VC_E = 2 * AC + IC;    // generic period entry
  constexpr int VC_L = AC;             // final-tap entry
  constexpr int NSLAB = (NK > 1) ? 4 : 1;

  __shared__ __attribute__((aligned(16))) u16 Bs[NSLAB][BSZ];

  const int tid = threadIdx.x;
  const int lane = tid & 63;
  const int wave = tid >> 6;
  const int n0 = blockIdx.x * BM;
  const int lr = lane & 15;
  const int lh = lane >> 4;
  const int row0 = wave * 32;

  f32x4 acc[M_REP][N_REP];
#pragma unroll
  for (int i = 0; i < M_REP; ++i)
#pragma unroll
    for (int j = 0; j < N_REP; ++j) acc[i][j] = (f32x4){0.f, 0.f, 0.f, 0.f};

  bf16x8 S0[M_REP][KK], S1[M_REP][KK], S2[M_REP][KK];
  int I0[2][M_REP], I1[2][M_REP];

  auto stage1 = [&](int k, int slab) {
    const u16* src = Wt + (size_t)k * BSZ;
    u16* dst = &Bs[(NK > 1) ? slab : 0][0];
#pragma unroll
    for (int i = 0; i < BISS; ++i) {
      int cb = i * 512 + wave * 64;
      if (BCH % 512 == 0 || cb < BCH)
        GLDS16(src + (size_t)(cb + lane) * 8, dst + (size_t)cb * 8);
    }
  };
  auto loadIdxPair = [&](int p, int (&m)[2][M_REP]) {
#pragma unroll
    for (int t = 0; t < 2; ++t)
#pragma unroll
      for (int mr = 0; mr < M_REP; ++mr)
        m[t][mr] = idxt[(size_t)(2 * p + t) * NPTS + n0 + row0 + mr * 16 + lr];
  };
  auto issueA = [&](const int (&m)[M_REP], bf16x8 (&dst)[M_REP][KK]) {
#pragma unroll
    for (int mr = 0; mr < M_REP; ++mr)
#pragma unroll
      for (int kk = 0; kk < KK; ++kk)
        dst[mr][kk] = *(const bf16x8*)(x + (size_t)m[mr] * CIN + kk * 32 + lh * 8);
  };
  auto compute = [&](int slab, const bf16x8 (&AR)[M_REP][KK]) {
    const u16* bsp = &Bs[(NK > 1) ? slab : 0][0];
#pragma unroll
    for (int kk = 0; kk < KK; ++kk) {
      bf16x8 b[N_REP];
      int pc = (kk * 4 + lh) ^ (lr & SWZB);
#pragma unroll
      for (int nr = 0; nr < N_REP; ++nr)
        b[nr] = *(const bf16x8*)(bsp + (size_t)(nr * 16 + lr) * CIN + pc * 8);
#pragma unroll
      for (int mr = 0; mr < M_REP; ++mr)
#pragma unroll
        for (int nr = 0; nr < N_REP; ++nr)
          acc[mr][nr] = __builtin_amdgcn_mfma_f32_16x16x32_bf16(AR[mr][kk], b[nr], acc[mr][nr], 0, 0, 0);
    }
  };

#define SBAR __builtin_amdgcn_sched_barrier(0)

  if constexpr (NK == 1) {
    int m0[M_REP];
#pragma unroll
    for (int mr = 0; mr < M_REP; ++mr) m0[mr] = n0 + row0 + mr * 16 + lr;
    stage1(0, 0);
    issueA(m0, S0);
    __syncthreads();
    compute(0, S0);
  } else {
    loadIdxPair(0, I0);
    SBAR;
    stage1(0, 0); stage1(1, 1);
    SBAR;
    issueA(I0[0], S0);
    SBAR;
    issueA(I0[1], S1);
    SBAR;
    loadIdxPair(1, I1);
    SBAR;

#define PERX(p, SA, SB, SC, IU, IW, C0, C1, N0, N1)                           \
    waitcnt_vm<VC_E>();                                                       \
    __builtin_amdgcn_s_barrier();                                             \
    SBAR;                                                                     \
    stage1(2 * (p) + 2, N0);                                                  \
    stage1(2 * (p) + 3, N1);                                                  \
    SBAR;                                                                     \
    issueA(IU[0], SC);                                                        \
    SBAR;                                                                     \
    loadIdxPair((p) + 2, IW);                                                 \
    SBAR;                                                                     \
    compute(C0, SA);                                                          \
    SBAR;                                                                     \
    issueA(IU[1], SA);                                                        \
    SBAR;                                                                     \
    compute(C1, SB);                                                          \
    SBAR;

#define SIXP(pb)                                                              \
    PERX(pb + 0, S0, S1, S2, I1, I0, 0, 1, 2, 3)                              \
    PERX(pb + 1, S2, S0, S1, I0, I1, 2, 3, 0, 1)                              \
    PERX(pb + 2, S1, S2, S0, I1, I0, 0, 1, 2, 3)                              \
    PERX(pb + 3, S0, S1, S2, I0, I1, 2, 3, 0, 1)                              \
    PERX(pb + 4, S2, S0, S1, I1, I0, 0, 1, 2, 3)                              \
    PERX(pb + 5, S1, S2, S0, I0, I1, 2, 3, 0, 1)

    SIXP(0)
    SIXP(6)
    // p = 12 (taps 24,25): stage tap 26 only; A(26)->S2; no idx, no A(27)
    waitcnt_vm<VC_E>();
    __builtin_amdgcn_s_barrier();
    SBAR;
    stage1(26, 2);
    SBAR;
    issueA(I1[0], S2);
    SBAR;
    compute(0, S0);
    SBAR;
    compute(1, S1);
    SBAR;
    waitcnt_vm<VC_L>();
    __builtin_amdgcn_s_barrier();
    SBAR;
    compute(2, S2);
#undef SIXP
#undef PERX
  }
#undef SBAR

#pragma unroll
  for (int mr = 0; mr < M_REP; ++mr) {
#pragma unroll
    for (int nr = 0; nr < N_REP; ++nr) {
      int col = nr * 16 + lr;
      float bv = bias ? bias[col] : 0.0f;
#pragma unroll
      for (int j = 0; j < 4; ++j) {
        int n = n0 + row0 + mr * 16 + lh * 4 + j;
        float v = acc[mr][nr][j] + bv;
        if (EMODE == 1) v = fmaxf(v, 0.0f);
        else if (EMODE == 2) v = fmaxf(v + b2f(res[(size_t)n * res_stride + col]), 0.0f);
        else if (EMODE == 3) v = fmaxf(v, 0.0f) + b2f(res[(size_t)n * res_stride + col]);
        if (OUTF32) ((float*)yout)[(size_t)n * out_stride + col] = v;
        else ((u16*)yout)[(size_t)n * out_stride + col] = f2b(v);
      }
    }
  }
}

// Fused q/k/v projections: A rows loaded to regs ONCE, 3 weight slabs staged
// through one LDS buffer sequentially.
__global__ __launch_bounds__(512, 2)
void qkv_k(const u16* __restrict__ x, const u16* __restrict__ Wt,
           u16* __restrict__ qo, u16* __restrict__ ko, u16* __restrict__ vo) {
  constexpr int CIN = 128, COUT = 128;
  constexpr int KK = 4, SWZB = 7, N_REP = 8, M_REP = 2;
  constexpr int BSZ = COUT * CIN;
  constexpr int BISS = (BSZ / 8) / 512;

  __shared__ __attribute__((aligned(16))) u16 Bs[BSZ];

  const int tid = threadIdx.x;
  const int lane = tid & 63;
  const int wave = tid >> 6;
  const int n0 = blockIdx.x * 256;
  const int lr = lane & 15;
  const int lh = lane >> 4;
  const int row0 = wave * 32;

  bf16x8 A0[M_REP][KK];
#pragma unroll
  for (int mr = 0; mr < M_REP; ++mr)
#pragma unroll
    for (int kk = 0; kk < KK; ++kk)
      A0[mr][kk] = *(const bf16x8*)(x + (size_t)(n0 + row0 + mr * 16 + lr) * CIN + kk * 32 + lh * 8);

  u16* outs[3] = {qo, ko, vo};
  for (int w = 0; w < 3; ++w) {
    if (w) __syncthreads();
    const u16* src = Wt + (size_t)w * BSZ;
#pragma unroll
    for (int i = 0; i < BISS; ++i) {
      int cb = i * 512 + wave * 64;
      GLDS16(src + (size_t)(cb + lane) * 8, &Bs[(size_t)cb * 8]);
    }
    __syncthreads();

    f32x4 acc[M_REP][N_REP];
#pragma unroll
    for (int i = 0; i < M_REP; ++i)
#pragma unroll
      for (int j = 0; j < N_REP; ++j) acc[i][j] = (f32x4){0.f, 0.f, 0.f, 0.f};
#pragma unroll
    for (int kk = 0; kk < KK; ++kk) {
      bf16x8 b[N_REP];
      int pc = (kk * 4 + lh) ^ (lr & SWZB);
#pragma unroll
      for (int nr = 0; nr < N_REP; ++nr)
        b[nr] = *(const bf16x8*)(&Bs[(size_t)(nr * 16 + lr) * CIN + pc * 8]);
#pragma unroll
      for (int mr = 0; mr < M_REP; ++mr)
#pragma unroll
        for (int nr = 0; nr < N_REP; ++nr)
          acc[mr][nr] = __builtin_amdgcn_mfma_f32_16x16x32_bf16(A0[mr][kk], b[nr], acc[mr][nr], 0, 0, 0);
    }
    u16* yo = outs[w];
#pragma unroll
    for (int mr = 0; mr < M_REP; ++mr)
#pragma unroll
      for (int nr = 0; nr < N_REP; ++nr) {
        int col = nr * 16 + lr;
#pragma unroll
        for (int j = 0; j < 4; ++j) {
          int n = n0 + row0 + mr * 16 + lh * 4 + j;
          yo[(size_t)n * 128 + col] = f2b(acc[mr][nr][j]);
        }
      }
  }
}

// kNN attention: 16 lanes per point, 4 points per wave.
__global__ __launch_bounds__(256)
void attn_k(const u16* __restrict__ qb, const u16* __restrict__ kb,
            const u16* __restrict__ vb, const int* __restrict__ knn,
            u16* __restrict__ agg) {
  const int t = blockIdx.x * 256 + threadIdx.x;
  const int n = t >> 4;
  const int s = t & 15;
  const int lane = threadIdx.x & 63;
  const int gbase = lane & 48;

  int myidx = knn[n * KNN + s];

  bf16x8 q8 = *(const bf16x8*)(qb + (size_t)n * 128 + s * 8);
  float qf[8];
#pragma unroll
  for (int c = 0; c < 4; ++c) {
    uint32_t u = ((const uint32_t*)&q8)[c];
    qf[2 * c] = b2f((u16)(u & 0xffff));
    qf[2 * c + 1] = b2f((u16)(u >> 16));
  }

  float lg[KNN];
  int ms[KNN];
#pragma unroll
  for (int j = 0; j < KNN; ++j) {
    int mj = __shfl(myidx, gbase | j);
    ms[j] = mj;
    bf16x8 k8 = *(const bf16x8*)(kb + (size_t)mj * 128 + s * 8);
    float d = 0.f;
#pragma unroll
    for (int c = 0; c < 4; ++c) {
      uint32_t u = ((const uint32_t*)&k8)[c];
      d += qf[2 * c] * b2f((u16)(u & 0xffff));
      d += qf[2 * c + 1] * b2f((u16)(u >> 16));
    }
    d += __shfl_xor(d, 1);
    d += __shfl_xor(d, 2);
    d += __shfl_xor(d, 4);
    d += __shfl_xor(d, 8);
    lg[j] = d * 0.08838834764831845f;
  }
  float mx = lg[0];
#pragma unroll
  for (int j = 1; j < KNN; ++j) mx = fmaxf(mx, lg[j]);
  float ssum = 0.f;
#pragma unroll
  for (int j = 0; j < KNN; ++j) { lg[j] = __expf(lg[j] - mx); ssum += lg[j]; }
  float inv = 1.0f / ssum;

  float a[8] = {0, 0, 0, 0, 0, 0, 0, 0};
#pragma unroll
  for (int j = 0; j < KNN; ++j) {
    bf16x8 v8 = *(const bf16x8*)(vb + (size_t)ms[j] * 128 + s * 8);
    float w = lg[j];
#pragma unroll
    for (int c = 0; c < 4; ++c) {
      uint32_t u = ((const uint32_t*)&v8)[c];
      a[2 * c] += w * b2f((u16)(u & 0xffff));
      a[2 * c + 1] += w * b2f((u16)(u >> 16));
    }
  }
  uint32_t ow[4];
#pragma unroll
  for (int c = 0; c < 4; ++c)
    ow[c] = (uint32_t)f2b(a[2 * c] * inv) | ((uint32_t)f2b(a[2 * c + 1] * inv) << 16);
  *(uint32_t*)(agg + (size_t)n * 128 + s * 8 + 0) = ow[0];
  *(uint32_t*)(agg + (size_t)n * 128 + s * 8 + 2) = ow[1];
  *(uint32_t*)(agg + (size_t)n * 128 + s * 8 + 4) = ow[2];
  *(uint32_t*)(agg + (size_t)n * 128 + s * 8 + 6) = ow[3];
}

extern "C" void kernel_launch(void* const* d_in, const int* in_sizes, int n_in,
                              void* d_out, int out_size, void* d_ws, size_t ws_size,
                              hipStream_t stream) {
  (void)in_sizes; (void)n_in; (void)out_size; (void)ws_size;
  const float* feats = (const float*)d_in[0];
  const int*   nbr   = (const int*)d_in[1];
  const int*   knn   = (const int*)d_in[2];
  const float* W_in  = (const float*)d_in[3];
  const float* b_in  = (const float*)d_in[4];
  const float* W_c0  = (const float*)d_in[5];
  const float* b_c0  = (const float*)d_in[6];
  const float* W_c1  = (const float*)d_in[7];
  const float* b_c1  = (const float*)d_in[8];
  const float* Wq    = (const float*)d_in[9];
  const float* Wk    = (const float*)d_in[10];
  const float* Wv    = (const float*)d_in[11];
  const float* Wo    = (const float*)d_in[12];
  const float* bo    = (const float*)d_in[13];
  const float* Wa0   = (const float*)d_in[14];
  const float* ba0   = (const float*)d_in[15];
  const float* Wa1   = (const float*)d_in[16];
  const float* ba1   = (const float*)d_in[17];
  const float* Wa2   = (const float*)d_in[18];
  const float* ba2   = (const float*)d_in[19];
  const float* Wb0   = (const float*)d_in[20];
  const float* bb0   = (const float*)d_in[21];
  const float* Wb1   = (const float*)d_in[22];
  const float* bb1   = (const float*)d_in[23];
  const float* W_out = (const float*)d_in[24];
  const float* b_out = (const float*)d_in[25];

  char* ws = (char*)d_ws;
  size_t off = 0;
  auto alloc = [&](size_t bytes) { size_t r = off; off += (bytes + 255) & ~(size_t)255; return r; };

  u16* wt_c0  = (u16*)(ws + alloc((size_t)81 * 16384 * 2));
  u16* wt_c1  = (u16*)(ws + alloc((size_t)81 * 16384 * 2));
  u16* wt_qkv = (u16*)(ws + alloc((size_t)9 * 16384 * 2));
  u16* wt_o   = (u16*)(ws + alloc((size_t)3 * 16384 * 2));
  u16* wt_a0  = (u16*)(ws + alloc((size_t)3 * 128 * 32 * 2));
  u16* wt_a1  = (u16*)(ws + alloc((size_t)81 * 32 * 32 * 2));
  u16* wt_a2  = (u16*)(ws + alloc((size_t)3 * 32 * 64 * 2));
  u16* wt_b0  = (u16*)(ws + alloc((size_t)81 * 128 * 32 * 2));
  u16* wt_b1  = (u16*)(ws + alloc((size_t)81 * 32 * 64 * 2));
  u16* wt_out = (u16*)(ws + alloc((size_t)27 * 16384 * 2));
  u16* wt_in  = (u16*)(ws + alloc((size_t)128 * 32 * 2));
  int* idx_t  = (int*)(ws + alloc((size_t)(NK27 + 1) * NPTS * 4));  // +1 row: pair-tail overread
  u16* G27    = (u16*)(ws + alloc((size_t)NPTS * 32 * 2));

  u16* B0 = (u16*)(ws + alloc((size_t)(NPTS + 1) * 128 * 2));
  u16* B1 = (u16*)(ws + alloc((size_t)NPTS * 128 * 2));
  u16* KB = (u16*)(ws + alloc((size_t)(NPTS + 1) * 128 * 2));
  u16* VB = (u16*)(ws + alloc((size_t)(NPTS + 1) * 128 * 2));
  u16* QB = (u16*)(ws + alloc((size_t)NPTS * 128 * 2));
  u16* H1 = (u16*)(ws + alloc((size_t)(NPTS + 1) * 32 * 2));
  u16* HA = (u16*)(ws + alloc((size_t)NPTS * 32 * 2));
  u16* G  = (u16*)(ws + alloc((size_t)(NPTS + 1) * 32 * 2));
  u16* AGG = B0;
  u16* B2 = KB;
  u16* B3 = VB;

  // tiled weight prep (coalesced): grid = (tiles_ci*tiles_co, G)
  wtrans_t<<<dim3(16, 81), 256, 0, stream>>>(W_c0, wt_c0, 128, 128, 16384);
  wtrans_t<<<dim3(16, 81), 256, 0, stream>>>(W_c1, wt_c1, 128, 128, 16384);
  wtrans_t<<<dim3(16, 3), 256, 0, stream>>>(Wq, wt_qkv + 0 * 16384, 128, 128, 3 * 16384);
  wtrans_t<<<dim3(16, 3), 256, 0, stream>>>(Wk, wt_qkv + 1 * 16384, 128, 128, 3 * 16384);
  wtrans_t<<<dim3(16, 3), 256, 0, stream>>>(Wv, wt_qkv + 2 * 16384, 128, 128, 3 * 16384);
  wtrans_t<<<dim3(16, 3), 256, 0, stream>>>(Wo, wt_o, 128, 128, 16384);
  wtrans_t<<<dim3(4, 3), 256, 0, stream>>>(Wa0, wt_a0, 128, 32, 4096);
  wtrans_t<<<dim3(1, 81), 256, 0, stream>>>(Wa1, wt_a1, 32, 32, 1024);
  wtrans_t<<<dim3(2, 3), 256, 0, stream>>>(Wa2, wt_a2, 32, 64, 2048);
  wtrans_t<<<dim3(4, 81), 256, 0, stream>>>(Wb0, wt_b0, 128, 32, 4096);
  wtrans_t<<<dim3(2, 81), 256, 0, stream>>>(Wb1, wt_b1, 32, 64, 2048);
  wtrans_t<<<dim3(16, 27), 256, 0, stream>>>(W_out, wt_out, 128, 128, 16384);
  wtrans_in<<<16, 256, 0, stream>>>(W_in, wt_in);
  itrans_t<<<NPTS / 256, 256, 0, stream>>>(nbr, idx_t);

  zero_pads<<<1, 256, 0, stream>>>(B0 + (size_t)NPTS * 128, KB + (size_t)NPTS * 128,
                                   VB + (size_t)NPTS * 128, H1 + (size_t)NPTS * 32,
                                   G + (size_t)NPTS * 32);

  g27<<<NPTS * 32 / 256, 256, 0, stream>>>(feats, nbr, G27);
  sconv<32, 128, 1, 0, false><<<NPTS / 256, 512, 0, stream>>>(G27, nullptr, wt_in, b_in, nullptr, 0, B0, 128);

  const int GB = NPTS / 256;
  for (int s = 0; s < 3; ++s) {
    const u16* wc0 = wt_c0 + (size_t)s * 27 * 16384;
    const u16* wc1 = wt_c1 + (size_t)s * 27 * 16384;
    const u16* wqkv = wt_qkv + (size_t)s * 3 * 16384;
    const u16* wos = wt_o + (size_t)s * 16384;
    const u16* wa0 = wt_a0 + (size_t)s * 4096;
    const u16* wa1 = wt_a1 + (size_t)s * 27648;
    const u16* wa2 = wt_a2 + (size_t)s * 2048;
    const u16* wb0 = wt_b0 + (size_t)s * 110592;
    const u16* wb1 = wt_b1 + (size_t)s * 55296;

    sconv<128, 128, 27, 0, false><<<GB, 512, 0, stream>>>(B0, idx_t, wc0, b_c0 + s * 128, nullptr, 0, B1, 128);
    qkv_k<<<GB, 512, 0, stream>>>(B1, wqkv, QB, KB, VB);
    attn_k<<<NPTS / 16, 256, 0, stream>>>(QB, KB, VB, knn, AGG);
    sconv<128, 128, 1, 2, false><<<GB, 512, 0, stream>>>(AGG, nullptr, wos, bo + s * 128, B1, 128, B2, 128);
    sconv<128, 128, 27, 0, false><<<GB, 512, 0, stream>>>(B2, idx_t, wc1, b_c1 + s * 128, nullptr, 0, B3, 128);
    sconv<128, 32, 1, 1, false><<<GB, 512, 0, stream>>>(B3, nullptr, wa0, ba0 + s * 32, nullptr, 0, H1, 32);
    sconv<32, 32, 27, 1, false><<<GB, 512, 0, stream>>>(H1, idx_t, wa1, ba1 + s * 32, nullptr, 0, HA, 32);
    sconv<32, 64, 1, 3, false><<<GB, 512, 0, stream>>>(HA, idx_t, wa2, ba2 + s * 64, B3, 128, B0, 128);
    sconv<128, 32, 27, 1, false><<<GB, 512, 0, stream>>>(B3, idx_t, wb0, bb0 + s * 32, nullptr, 0, G, 32);
    sconv<32, 64, 27, 3, false><<<GB, 512, 0, stream>>>(G, idx_t, wb1, bb1 + s * 64, B3 + 64, 128, (void*)(B0 + 64), 128);
  }
  sconv<128, 128, 27, 0, true><<<GB, 512, 0, stream>>>(B0, idx_t, wt_out, b_out, nullptr, 0, d_out, 128);
}